// Round 6
// baseline (5889.784 us; speedup 1.0000x reference)
//
#include <hip/hip_runtime.h>
#include <hip/hip_bf16.h>
#include <math.h>

// InstructPerceiverResampler on MI355X (gfx950).
// Round 6: gemm256 ds_read software pipelining (the real T4):
//   P0 issues ALL 16 mh0 reads (a0,b0,a1,b1), waits lgkmcnt(8)  -> a0,b0
//   P1 issues a0<-mh1ks0 (4),                waits lgkmcnt(4)  -> a1,b1
//   P2 issues a1<-mh1ks1 (4),                waits lgkmcnt(4)  -> a0'
//   P3 issues nothing,                       waits lgkmcnt(0)  -> a1'
// so each phase's LDS drain hides under the previous phase's MFMA burst.
// Barrier/vmcnt skeleton identical to R3-R5 (refcheck-passed).

typedef __attribute__((ext_vector_type(4))) float f32x4;
typedef __attribute__((ext_vector_type(8))) short bf16x8;
typedef unsigned int u32;

#define DEV __device__ __forceinline__

DEV float bf2f(short s){ union{u32 u; float f;} v; v.u = ((u32)(unsigned short)s) << 16; return v.f; }
DEV short f2bf(float f){
  union{float f; u32 u;} v; v.f = f;
  u32 r = (v.u + 0x7FFFu + ((v.u >> 16) & 1u)) >> 16;
  return (short)r;
}

// LDS byte-offset of a __shared__ pointer (AS(3) pointers are 32-bit)
DEV u32 lds_off(const short* p){
  return (u32)(uintptr_t)(__attribute__((address_space(3))) const short*)p;
}
// opaque ds_read_b128 (compiler can't see the LDS dependency -> no auto-waits)
DEV bf16x8 dsr(u32 addr){
  bf16x8 r;
  asm volatile("ds_read_b128 %0, %1" : "=v"(r) : "v"(addr));
  return r;
}

// ---------------------------------------------------------------------------
// 256x256 8-phase GEMM: C[m,n] = A[m,k]*B[n,k] (+bias)(+gelu), bf16 in/out.
// CMAP 0: C[gm*ldc+gn]
// CMAP 1: (kv x-part)  C[(gm/729*857 + gm%729)*3072 + gn]
// CMAP 2: (fused q|kv) gn<1536 -> C[gm*1536+gn]*SCALE ; else
//                      C2[((gm>>7)*857+729+(gm&127))*3072 + gn-1536]
// ---------------------------------------------------------------------------
template<int GELU, int BIAS, int CMAP>
__global__ __launch_bounds__(512, 2)
void gemm256(const short* __restrict__ A, const short* __restrict__ Bm,
             short* __restrict__ C, short* __restrict__ C2,
             const float* __restrict__ bias,
             int K, int lda, int ldb, int ldc,
             int Mvalid, int NBmax, int Nwrite)
{
  __shared__ __align__(16) short LDS[65536];   // 128 KiB: [buf][A(16384)|B(16384)]

  int nwg = gridDim.x * gridDim.y;
  int bid = blockIdx.y * gridDim.x + blockIdx.x;
  if ((nwg & 7) == 0){
    int chunk = nwg >> 3;
    bid = (bid & 7) * chunk + (bid >> 3);
  }
  int by = bid / gridDim.x;
  int m0 = by * 256;
  int n0 = (bid - by * gridDim.x) * 256;

  int tid = threadIdx.x;
  int lane = tid & 63;
  int w = tid >> 6;           // 0..7
  int wr = w >> 2, wc = w & 3;

  // stage constants: lane covers row (w*8 + sl), 16B-block (lane&7);
  // source col-block is (lane&7)^sl (XOR swizzle; gload_lds dest stays linear).
  int sl = lane >> 3;
  int scol = ((lane & 7) ^ sl) * 8;     // shorts

  // hoisted staging pointers: [reg][chunk], reg: 0 Blo 1 Bhi 2 Alo 3 Ahi
  const short* gsrc[4][2];
  {
    int rb = n0 + w*8 + sl;
    int ra = m0 + w*8 + sl;
    int rows[4][2] = {{rb, rb+64},{rb+128, rb+192},{ra, ra+64},{ra+128, ra+192}};
#pragma unroll
    for (int r=0;r<4;r++){
#pragma unroll
      for (int c2=0;c2<2;c2++){
        int rr = rows[r][c2];
        int lim = (r < 2) ? (NBmax-1) : (Mvalid-1);
        if (rr > lim) rr = lim;
        const short* bp = (r < 2) ? Bm : A;
        int ld = (r < 2) ? ldb : lda;
        gsrc[r][c2] = bp + (long)rr*ld + scol;
      }
    }
  }
  char* ldst[4][2];
#pragma unroll
  for (int r=0;r<4;r++){
    int sbase = ((r & 2) ? 0 : 16384) + (r & 1)*8192;   // shorts
    ldst[r][0] = (char*)LDS + (sbase + (w*8)*64)*2;
    ldst[r][1] = (char*)LDS + (sbase + (64 + w*8)*64)*2;
  }

#define GLDS(src, dst) __builtin_amdgcn_global_load_lds( \
      (const __attribute__((address_space(1))) u32*)(src), \
      (__attribute__((address_space(3))) u32*)(dst), 16, 0, 0)
#define STAGE(reg, tau) do { \
    int _bo = ((tau) & 1) ? 65536 : 0; \
    GLDS(gsrc[reg][0] + (tau)*64, ldst[reg][0] + _bo); \
    GLDS(gsrc[reg][1] + (tau)*64, ldst[reg][1] + _bo); \
  } while(0)

  // reader constants (byte offsets for asm ds_read)
  int rsel = lane & 15;
  int g4 = lane >> 4;
  int xr = rsel & 7;
  u32 blk0 = (u32)((g4 ^ xr) * 16);            // ks=0 swizzled block (bytes)
  u32 blk1 = (u32)(((4 + g4) ^ xr) * 16);      // ks=1
  u32 aA = lds_off(LDS) + (u32)((wr*128 + rsel)*128);            // A row base
  u32 bB = lds_off(LDS) + 32768u + (u32)((wc*64 + rsel)*128);    // B row base

  int nt = K >> 6;

  f32x4 acc[8][4];
#pragma unroll
  for (int i=0;i<8;i++)
#pragma unroll
    for (int j=0;j<4;j++) acc[i][j] = (f32x4){0.f,0.f,0.f,0.f};

  bf16x8 a0[4], a1[4], b0[4], b1[4];
  auto ldA = [&](bf16x8* a, int mh, u32 blkB, u32 bufo){
#pragma unroll
    for (int m=0;m<4;m++)
      a[m] = dsr(aA + bufo + (u32)((mh*64 + m*16)*128) + blkB);
  };
  auto ldB = [&](bf16x8* bq, u32 blkB, u32 bufo){
#pragma unroll
    for (int n=0;n<4;n++)
      bq[n] = dsr(bB + bufo + (u32)((n*16)*128) + blkB);
  };
  auto mm = [&](bf16x8* a, bf16x8* bq, int mh){
#pragma unroll
    for (int m=0;m<4;m++)
#pragma unroll
      for (int n=0;n<4;n++)
        acc[mh*4+m][n] = __builtin_amdgcn_mfma_f32_16x16x32_bf16(a[m], bq[n], acc[mh*4+m][n], 0, 0, 0);
  };

#define BAR() asm volatile("s_barrier" ::: "memory")
#define WAITL(N) do { \
    asm volatile("s_waitcnt lgkmcnt(" #N ")" ::: "memory"); \
    __builtin_amdgcn_sched_barrier(0); \
  } while(0)

  // prologue: tile0 complete + tile1's B halves (6 half-tiles, 12 loads/thread)
  STAGE(0,0); STAGE(1,0); STAGE(2,0); STAGE(3,0);
  STAGE(0,1); STAGE(1,1);

#pragma unroll 1
  for (int t=0; t<nt; ++t){
    u32 bufo = (u32)(t & 1) * 65536u;
    if (t == nt-1) { asm volatile("s_waitcnt vmcnt(0)" ::: "memory"); }
    else           { asm volatile("s_waitcnt vmcnt(4)" ::: "memory"); }
    BAR();
    // P0 pre: ALL mh0 reads (a0,b0 first, then a1,b1 — issue order matters)
    ldA(a0, 0, blk0, bufo); ldB(b0, blk0, bufo);
    ldA(a1, 0, blk1, bufo); ldB(b1, blk1, bufo);
    if (t+1 < nt) STAGE(2, t+1);
    BAR(); WAITL(8);                       // a0,b0 ready; a1,b1 in flight
    __builtin_amdgcn_s_setprio(1); mm(a0, b0, 0); __builtin_amdgcn_s_setprio(0);
    BAR();
    // P1 pre: recycle a0 <- (mh1, ks0)
    ldA(a0, 1, blk0, bufo);
    if (t+1 < nt) STAGE(3, t+1);
    BAR(); WAITL(4);                       // a1,b1 ready; a0' in flight
    __builtin_amdgcn_s_setprio(1); mm(a1, b1, 0); __builtin_amdgcn_s_setprio(0);
    BAR();
    // P2 pre: recycle a1 <- (mh1, ks1)
    ldA(a1, 1, blk1, bufo);
    if (t+2 < nt) STAGE(0, t+2);
    BAR(); WAITL(4);                       // a0' ready; a1' in flight
    __builtin_amdgcn_s_setprio(1); mm(a0, b0, 1); __builtin_amdgcn_s_setprio(0);
    BAR();
    // P3 pre: stage only
    if (t+2 < nt) STAGE(1, t+2);
    BAR(); WAITL(0);                       // a1' ready
    __builtin_amdgcn_s_setprio(1); mm(a1, b1, 1); __builtin_amdgcn_s_setprio(0);
  }
#undef BAR
#undef WAITL
#undef STAGE
#undef GLDS

  // epilogue: C/D frag layout col=lane&15, row=(lane>>4)*4+j
  int cq = (lane >> 4) * 4;
  int csel = lane & 15;
#pragma unroll
  for (int mi=0; mi<8; mi++){
#pragma unroll
    for (int n=0; n<4; n++){
#pragma unroll
      for (int j=0; j<4; j++){
        int gm = m0 + wr*128 + mi*16 + cq + j;
        int gn = n0 + wc*64 + n*16 + csel;
        if (gm < Mvalid && gn < Nwrite){
          float v = acc[mi][n][j];
          if (BIAS) v += bias[gn];
          if (GELU) v = 0.5f*v*(1.0f + erff(v*0.70710678118654752f));
          if (CMAP == 0){
            C[(long)gm*ldc + gn] = f2bf(v);
          } else if (CMAP == 1){
            int bb = gm / 729;
            int jj = gm - bb*729;
            C[((long)bb*857 + jj)*3072 + gn] = f2bf(v);
          } else {
            if (gn < 1536){
              C[(long)gm*1536 + gn] = f2bf(v * 0.1020620726159657f);
            } else {
              int bb = gm >> 7, jj = gm & 127;
              C2[((long)bb*857 + 729 + jj)*3072 + (gn - 1536)] = f2bf(v);
            }
          }
        }
      }
    }
  }
}

// ---------------------------------------------------------------------------
// 128x128 2-phase GEMM (verified r2) for small/batched shapes.
// ---------------------------------------------------------------------------
template<int GELU, int BIAS, int RES, int OUTF32>
__global__ __launch_bounds__(256)
void gemm_t(const short* __restrict__ A, const short* __restrict__ B,
            void* __restrict__ C, const float* __restrict__ bias,
            const float* __restrict__ res,
            int K, int lda, int ldb, int ldc,
            int Mvalid, int NBmax, int Nwrite,
            int zdiv, long sA1, long sA2, long sB1, long sB2, long sC1, long sC2,
            float scale)
{
  __shared__ __align__(16) short As[2][128*32];
  __shared__ __align__(16) short Bs[2][128*32];

  int z = blockIdx.z;
  int zq = z / zdiv, zr = z - zq*zdiv;
  const short* Ab = A + zq*sA1 + zr*sA2;
  const short* Bb = B + zq*sB1 + zr*sB2;
  long cOff = zq*sC1 + zr*sC2;
  int m0 = blockIdx.y * 128;
  int n0 = blockIdx.x * 128;
  int tid = threadIdx.x;
  int lane = tid & 63;
  int w = tid >> 6;
  int wm = (w >> 1) * 64, wn = (w & 1) * 64;

  int sr = lane >> 2;
  int sc = (lane & 3) * 8;
  int ar0 = m0 + w*32 + sr;
  int br0 = n0 + w*32 + sr;

  int raA0 = ar0;      if (raA0 > Mvalid-1) raA0 = Mvalid-1;
  int raA1 = ar0 + 16; if (raA1 > Mvalid-1) raA1 = Mvalid-1;
  int rbB0 = br0;      if (rbB0 > NBmax-1) rbB0 = NBmax-1;
  int rbB1 = br0 + 16; if (rbB1 > NBmax-1) rbB1 = NBmax-1;
  const short* gA0 = Ab + (long)raA0*lda + sc;
  const short* gA1 = Ab + (long)raA1*lda + sc;
  const short* gB0 = Bb + (long)rbB0*ldb + sc;
  const short* gB1 = Bb + (long)rbB1*ldb + sc;
  int ldsRow0 = (w*32)*32;
  int ldsRow1 = (w*32 + 16)*32;

  f32x4 acc[4][4];
#pragma unroll
  for (int i=0;i<4;i++)
#pragma unroll
    for (int j=0;j<4;j++) acc[i][j] = (f32x4){0.f,0.f,0.f,0.f};

  auto stage = [&](int buf, int kb){
    __builtin_amdgcn_global_load_lds(
        (const __attribute__((address_space(1))) u32*)(gA0 + kb),
        (__attribute__((address_space(3))) u32*)(&As[buf][ldsRow0]), 16, 0, 0);
    __builtin_amdgcn_global_load_lds(
        (const __attribute__((address_space(1))) u32*)(gA1 + kb),
        (__attribute__((address_space(3))) u32*)(&As[buf][ldsRow1]), 16, 0, 0);
    __builtin_amdgcn_global_load_lds(
        (const __attribute__((address_space(1))) u32*)(gB0 + kb),
        (__attribute__((address_space(3))) u32*)(&Bs[buf][ldsRow0]), 16, 0, 0);
    __builtin_amdgcn_global_load_lds(
        (const __attribute__((address_space(1))) u32*)(gB1 + kb),
        (__attribute__((address_space(3))) u32*)(&Bs[buf][ldsRow1]), 16, 0, 0);
  };

  int nt = K >> 5;
  stage(0, 0);
  __syncthreads();

  int kq = (lane >> 4) * 8;
  int rsel = lane & 15;
  int cur = 0;
  for (int t = 0; t < nt; ++t){
    if (t + 1 < nt) stage(cur ^ 1, (t+1)*32);

    bf16x8 af[4], bfr[4];
#pragma unroll
    for (int m=0;m<4;m++) af[m]  = *(const bf16x8*)&As[cur][(wm + m*16 + rsel)*32 + kq];
#pragma unroll
    for (int n=0;n<4;n++) bfr[n] = *(const bf16x8*)&Bs[cur][(wn + n*16 + rsel)*32 + kq];
#pragma unroll
    for (int m=0;m<4;m++)
#pragma unroll
      for (int n=0;n<4;n++)
        acc[m][n] = __builtin_amdgcn_mfma_f32_16x16x32_bf16(af[m], bfr[n], acc[m][n], 0, 0, 0);

    __syncthreads();
    cur ^= 1;
  }

  int cq = (lane >> 4) * 4;
  int csel = lane & 15;
#pragma unroll
  for (int m=0;m<4;m++){
#pragma unroll
    for (int n=0;n<4;n++){
#pragma unroll
      for (int j=0;j<4;j++){
        int gm = m0 + wm + m*16 + cq + j;
        int gn = n0 + wn + n*16 + csel;
        if (gm < Mvalid && gn < Nwrite){
          float v = acc[m][n][j] * scale;
          if (BIAS) v += bias[gn];
          if (GELU) v = 0.5f*v*(1.0f + erff(v*0.70710678118654752f));
          long off = cOff + (long)gm*ldc + gn;
          if (OUTF32){
            float rv = RES ? res[off] : 0.0f;
            ((float*)C)[off] = v + rv;
          } else {
            ((short*)C)[off] = f2bf(v);
          }
        }
      }
    }
  }
}

// ---------------------------------------------------------------------------
__global__ __launch_bounds__(256)
void convT(const float* __restrict__ in, short* __restrict__ out,
           int K, int N, const float* __restrict__ s)
{
  __shared__ float tile[32][33];
  int kb = blockIdx.y*32, nb = blockIdx.x*32;
  int tx = threadIdx.x & 31, ty = threadIdx.x >> 5;
  for (int i = ty; i < 32; i += 8){
    int k = kb + i, n = nb + tx;
    float v = 0.f;
    if (k < K && n < N){ v = in[(long)k*N + n]; if (s) v *= s[k]; }
    tile[i][tx] = v;
  }
  __syncthreads();
  for (int i = ty; i < 32; i += 8){
    int n = nb + i, k = kb + tx;
    if (n < N && k < K) out[(long)n*K + k] = f2bf(tile[tx][i]);
  }
}

__global__ __launch_bounds__(256)
void biasfold(const float* __restrict__ W, const float* __restrict__ bvec, float* __restrict__ outb)
{
  int n = blockIdx.x*256 + threadIdx.x;
  float s = 0.f;
  for (int k=0;k<1152;k++) s += bvec[k]*W[(long)k*3072 + n];
  outb[n] = s;
}

__global__ __launch_bounds__(256)
void cvt_bf16x4(const float* __restrict__ in, short* __restrict__ o, long n)
{
  long i = ((long)blockIdx.x*256 + threadIdx.x)*4;
  if (i >= n) return;
  float4 v = *(const float4*)(in + i);
  o[i+0]=f2bf(v.x); o[i+1]=f2bf(v.y); o[i+2]=f2bf(v.z); o[i+3]=f2bf(v.w);
}

__global__ __launch_bounds__(256)
void latcopy(const float* __restrict__ latents, float* __restrict__ lat)
{
  int idx = blockIdx.x*256 + threadIdx.x;
  int d = idx % 1152; int j = (idx / 1152) % 64; int b = idx / (1152*64);
  lat[((long)b*128 + j)*1152 + d] = latents[j*1152 + d];
}

__global__ __launch_bounds__(256)
void transV(const short* __restrict__ kv, short* __restrict__ Vt)
{
  int b = blockIdx.z;
  __shared__ short tile[32][33];
  int rb = blockIdx.y*32, cb = blockIdx.x*32;
  int tx = threadIdx.x & 31, ty = threadIdx.x >> 5;
  for (int i=ty; i<32; i+=8){
    int r = rb+i, c = cb+tx;
    short v = 0;
    if (r < 857) v = kv[((long)b*857 + r)*3072 + 1536 + c];
    tile[i][tx] = v;
  }
  __syncthreads();
  for (int i=ty;i<32;i+=8){
    int c = cb+i, r = rb+tx;
    Vt[((long)b*1536 + c)*864 + r] = tile[tx][i];
  }
}

__global__ __launch_bounds__(256)
void softmax_rows(short* __restrict__ SP)
{
  long row = (long)blockIdx.x*4 + (threadIdx.x >> 6);
  int lane = threadIdx.x & 63;
  short* p = SP + row*896;
  float vals[14];
  float mx = -1e30f;
#pragma unroll
  for (int i=0;i<14;i++){
    int j = i*64 + lane;
    float v = (j < 857) ? bf2f(p[j]) : -1e30f;
    vals[i] = v; mx = fmaxf(mx, v);
  }
#pragma unroll
  for (int o=32;o;o>>=1) mx = fmaxf(mx, __shfl_xor(mx, o));
  float s = 0.f;
#pragma unroll
  for (int i=0;i<14;i++){
    int j = i*64 + lane;
    float e = (j < 857) ? __expf(vals[i]-mx) : 0.f;
    vals[i] = e; s += e;
  }
#pragma unroll
  for (int o=32;o;o>>=1) s += __shfl_xor(s, o);
  float inv = 1.0f / s;
#pragma unroll
  for (int i=0;i<14;i++){
    int j = i*64 + lane;
    if (j < 864) p[j] = f2bf(j < 857 ? vals[i]*inv : 0.f);
  }
}

template<int OUTF32>
__global__ __launch_bounds__(256)
void ln_k(const float* __restrict__ in, void* __restrict__ outp,
          const float* __restrict__ w, const float* __restrict__ b,
          int grpSel, int grpStride)
{
  const int D = 1152;
  int r = blockIdx.x;
  long ir = (long)(r / grpSel)*grpStride + (r % grpSel);
  const float* x = in + ir*D;
  int tid = threadIdx.x;
  float s1=0.f, s2=0.f;
  float xv[5];
#pragma unroll
  for (int t=0;t<5;t++){
    int i = tid + t*256;
    xv[t] = (i < D) ? x[i] : 0.f;
    s1 += xv[t]; s2 += xv[t]*xv[t];
  }
#pragma unroll
  for (int o=32;o;o>>=1){ s1 += __shfl_xor(s1,o); s2 += __shfl_xor(s2,o); }
  __shared__ float red[8];
  int wid = tid>>6, lane = tid&63;
  if (lane==0){ red[wid]=s1; red[4+wid]=s2; }
  __syncthreads();
  s1 = red[0]+red[1]+red[2]+red[3];
  s2 = red[4]+red[5]+red[6]+red[7];
  float mu = s1 / D;
  float var = s2 / D - mu*mu;
  float rs = rsqrtf(var + 1e-5f);
#pragma unroll
  for (int t=0;t<5;t++){
    int i = tid + t*256;
    if (i >= D) break;
    float v = (xv[t]-mu)*rs;
    if (w) v = v*w[i] + b[i];
    if (OUTF32) ((float*)outp)[(long)r*D + i] = v;
    else        ((short*)outp)[(long)r*D + i] = f2bf(v);
  }
}

// ---------------------------------------------------------------------------

extern "C" void kernel_launch(void* const* d_in, const int* in_sizes, int n_in,
                              void* d_out, int out_size, void* d_ws, size_t ws_size,
                              hipStream_t stream)
{
  const float* x      = (const float*)d_in[0];
  const float* tein   = (const float*)d_in[1];
  const float* lat0   = (const float*)d_in[2];
  const float* txt_w1 = (const float*)d_in[3];
  const float* txt_b1 = (const float*)d_in[4];
  const float* txt_w2 = (const float*)d_in[5];
  const float* txt_b2 = (const float*)d_in[6];
  const float* nm_w   = (const float*)d_in[7];
  const float* nm_b   = (const float*)d_in[8];
  const float* nl_w   = (const float*)d_in[9];
  const float* nl_b   = (const float*)d_in[10];
  const float* Wq     = (const float*)d_in[11];
  const float* Wkv    = (const float*)d_in[12];
  const float* Wo     = (const float*)d_in[13];
  const float* ffln_w = (const float*)d_in[14];
  const float* ffln_b = (const float*)d_in[15];
  const float* ff_w1  = (const float*)d_in[16];
  const float* ff_w2  = (const float*)d_in[17];
  const float* oln_w  = (const float*)d_in[18];
  const float* oln_b  = (const float*)d_in[19];
  float* out = (float*)d_out;
  (void)in_sizes; (void)n_in; (void)out_size; (void)ws_size;

  char* base = (char*)d_ws;
  size_t off = 0;
  auto alloc = [&](size_t bytes)->char*{
    char* r = base + off;
    off += (bytes + 255) & ~(size_t)255;
    return r;
  };
  short* wT    = (short*)alloc(4608ULL*1152*2);
  float* biasf = (float*)alloc(3072*4);
  short* xnorm = (short*)alloc(23328ULL*1152*2);
  float* lat   = (float*)alloc(4096ULL*1152*4);
  short* lm    = (short*)alloc(4096ULL*1152*2);
  short* qb    = (short*)alloc(4096ULL*1536*2);
  short* kv    = (short*)alloc(27424ULL*3072*2);
  short* Vt    = (short*)alloc(32ULL*1536*864*2);
  short* SP    = (short*)alloc(65536ULL*896*2);
  short* attn  = (short*)alloc(4096ULL*1536*2);
  short* ffh   = (short*)alloc(4096ULL*4608*2);
  short* txtin = SP;
  short* txth  = SP + 2048ULL*4096;

  // ---- preamble ----
  cvt_bf16x4<<<8192,256,0,stream>>>(tein, txtin, 2048LL*4096);
  convT<<<dim3(36,128),256,0,stream>>>(txt_w1, wT, 4096, 1152, nullptr);
  gemm_t<1,1,0,0><<<dim3(9,16,1),256,0,stream>>>(txtin, wT, txth, txt_b1, nullptr,
      4096,4096,4096,1152, 2048,1152,1152, 1, 0,0,0,0,0,0, 1.f);
  convT<<<dim3(36,36),256,0,stream>>>(txt_w2, wT, 1152, 1152, nullptr);
  gemm_t<0,1,0,1><<<dim3(9,1,32),256,0,stream>>>(txth, wT, lat + 64*1152, txt_b2, nullptr,
      1152,1152,1152,1152, 64,1152,1152, 1, 64L*1152,0, 0,0, 128L*1152,0, 1.f);
  latcopy<<<9216,256,0,stream>>>(lat0, lat);

  ln_k<0><<<23328,256,0,stream>>>(x, xnorm, nullptr, nullptr, 1<<28, 0);

  for (int L=0; L<6; L++){
    const float* WqL  = Wq    + (size_t)L*1152*1536;
    const float* WkvL = Wkv   + (size_t)L*1152*3072;
    const float* WoL  = Wo    + (size_t)L*1536*1152;
    const float* fw1  = ff_w1 + (size_t)L*1152*4608;
    const float* fw2  = ff_w2 + (size_t)L*4608*1152;

    // lm = LN(lat; nl)
    ln_k<0><<<4096,256,0,stream>>>(lat, lm, nl_w + L*1152, nl_b + L*1152, 1<<28, 0);

    // fused q | kv-latent: wT = [Wq^T (1536 rows) ; Wkv^T (3072 rows)]
    convT<<<dim3(48,36),256,0,stream>>>(WqL, wT, 1152, 1536, nullptr);
    convT<<<dim3(96,36),256,0,stream>>>(WkvL, wT + 1536*1152, 1152, 3072, nullptr);
    gemm256<0,0,2><<<dim3(18,16),512,0,stream>>>(lm, wT, qb, kv, nullptr,
        1152,1152,1152,0, 4096, 4608, 4608);

    // kv x part (folded nm affine)
    convT<<<dim3(96,36),256,0,stream>>>(WkvL, wT, 1152, 3072, nm_w + L*1152);
    biasfold<<<12,256,0,stream>>>(WkvL, nm_b + L*1152, biasf);
    gemm256<0,1,1><<<dim3(12,92),512,0,stream>>>(xnorm, wT, kv, nullptr, biasf,
        1152,1152,1152,0, 23328, 3072, 3072);

    // Vt = V^T per batch
    transV<<<dim3(48,27,32),256,0,stream>>>(kv, Vt);

    // S = q . k^T
    gemm_t<0,0,0,0><<<dim3(7,1,512),256,0,stream>>>(qb, kv, SP, nullptr, nullptr,
        96,1536,3072,896, 128,857,896, 16,
        128L*1536,96, 857L*3072,96, 16L*128*896,128L*896, 1.f);
    softmax_rows<<<16384,256,0,stream>>>(SP);
    gemm_t<0,0,0,0><<<dim3(1,1,512),256,0,stream>>>(SP, Vt, attn, nullptr, nullptr,
        864,896,864,1536, 128,96,96, 16,
        16L*128*896,128L*896, 1536L*864,96L*864, 128L*1536,96, 1.f);

    // lat += attn @ Wo
    convT<<<dim3(36,48),256,0,stream>>>(WoL, wT, 1536, 1152, nullptr);
    gemm_t<0,0,1,1><<<dim3(9,32,1),256,0,stream>>>(attn, wT, lat, nullptr, lat,
        1536,1536,1536,1152, 4096,1152,1152, 1, 0,0,0,0,0,0, 1.f);

    // FF
    ln_k<0><<<4096,256,0,stream>>>(lat, lm, ffln_w + L*1152, ffln_b + L*1152, 1<<28, 0);
    convT<<<dim3(144,36),256,0,stream>>>(fw1, wT, 1152, 4608, nullptr);
    gemm256<1,0,0><<<dim3(18,16),512,0,stream>>>(lm, wT, ffh, nullptr, nullptr,
        1152,1152,1152,4608, 4096,4608,4608);
    convT<<<dim3(36,144),256,0,stream>>>(fw2, wT, 4608, 1152, nullptr);
    gemm_t<0,0,1,1><<<dim3(9,32,1),256,0,stream>>>(ffh, wT, lat, nullptr, lat,
        4608,4608,4608,1152, 4096,1152,1152, 1, 0,0,0,0,0,0, 1.f);
  }

  ln_k<1><<<2048,256,0,stream>>>(lat, out, oln_w, oln_b, 64, 128);
}

// Round 7
// 5781.495 us; speedup vs baseline: 1.0187x; 1.0187x over previous
//
#include <hip/hip_runtime.h>
#include <hip/hip_bf16.h>
#include <math.h>

// InstructPerceiverResampler on MI355X (gfx950).
// Round 7: gemm256 re-scheduled to ONE s_barrier + ONE vmcnt(0) per K-tile
// (was 8 barriers/K-tile in R3-R6 -> 8-wave rendezvous cost dominated).
// Per iteration: vmcnt(0); barrier; 16 ds_reads; STAGE whole next tile
// (opposite buffer); quadrant MFMAs with counted lgkmcnt(8/4/4/0) and
// register-recycled A-reads. Addressing/swizzle identical to R3-R6
// (refcheck-passed, bank-conflict-free).

typedef __attribute__((ext_vector_type(4))) float f32x4;
typedef __attribute__((ext_vector_type(8))) short bf16x8;
typedef unsigned int u32;

#define DEV __device__ __forceinline__

DEV float bf2f(short s){ union{u32 u; float f;} v; v.u = ((u32)(unsigned short)s) << 16; return v.f; }
DEV short f2bf(float f){
  union{float f; u32 u;} v; v.f = f;
  u32 r = (v.u + 0x7FFFu + ((v.u >> 16) & 1u)) >> 16;
  return (short)r;
}

// LDS byte-offset of a __shared__ pointer (AS(3) pointers are 32-bit)
DEV u32 lds_off(const short* p){
  return (u32)(uintptr_t)(__attribute__((address_space(3))) const short*)p;
}
// opaque ds_read_b128 (compiler can't see the LDS dependency -> no auto-waits)
DEV bf16x8 dsr(u32 addr){
  bf16x8 r;
  asm volatile("ds_read_b128 %0, %1" : "=v"(r) : "v"(addr));
  return r;
}

// ---------------------------------------------------------------------------
// 256x256 GEMM: C[m,n] = A[m,k]*B[n,k] (+bias)(+gelu), bf16 in/out.
// CMAP 0: C[gm*ldc+gn]
// CMAP 1: (kv x-part)  C[(gm/729*857 + gm%729)*3072 + gn]
// CMAP 2: (fused q|kv) gn<1536 -> C[gm*1536+gn]*SCALE ; else
//                      C2[((gm>>7)*857+729+(gm&127))*3072 + gn-1536]
// ---------------------------------------------------------------------------
template<int GELU, int BIAS, int CMAP>
__global__ __launch_bounds__(512, 2)
void gemm256(const short* __restrict__ A, const short* __restrict__ Bm,
             short* __restrict__ C, short* __restrict__ C2,
             const float* __restrict__ bias,
             int K, int lda, int ldb, int ldc,
             int Mvalid, int NBmax, int Nwrite)
{
  __shared__ __align__(16) short LDS[65536];   // 128 KiB: [buf][A(16384)|B(16384)]

  int nwg = gridDim.x * gridDim.y;
  int bid = blockIdx.y * gridDim.x + blockIdx.x;
  if ((nwg & 7) == 0){
    int chunk = nwg >> 3;
    bid = (bid & 7) * chunk + (bid >> 3);
  }
  int by = bid / gridDim.x;
  int m0 = by * 256;
  int n0 = (bid - by * gridDim.x) * 256;

  int tid = threadIdx.x;
  int lane = tid & 63;
  int w = tid >> 6;           // 0..7
  int wr = w >> 2, wc = w & 3;

  // stage constants: lane covers row (w*8 + sl), 16B-block (lane&7);
  // source col-block is (lane&7)^sl (XOR swizzle; gload_lds dest stays linear).
  int sl = lane >> 3;
  int scol = ((lane & 7) ^ sl) * 8;     // shorts

  // hoisted staging pointers: [reg][chunk], reg: 0 Blo 1 Bhi 2 Alo 3 Ahi
  const short* gsrc[4][2];
  {
    int rb = n0 + w*8 + sl;
    int ra = m0 + w*8 + sl;
    int rows[4][2] = {{rb, rb+64},{rb+128, rb+192},{ra, ra+64},{ra+128, ra+192}};
#pragma unroll
    for (int r=0;r<4;r++){
#pragma unroll
      for (int c2=0;c2<2;c2++){
        int rr = rows[r][c2];
        int lim = (r < 2) ? (NBmax-1) : (Mvalid-1);
        if (rr > lim) rr = lim;
        const short* bp = (r < 2) ? Bm : A;
        int ld = (r < 2) ? ldb : lda;
        gsrc[r][c2] = bp + (long)rr*ld + scol;
      }
    }
  }
  char* ldst[4][2];
#pragma unroll
  for (int r=0;r<4;r++){
    int sbase = ((r & 2) ? 0 : 16384) + (r & 1)*8192;   // shorts
    ldst[r][0] = (char*)LDS + (sbase + (w*8)*64)*2;
    ldst[r][1] = (char*)LDS + (sbase + (64 + w*8)*64)*2;
  }

#define GLDS(src, dst) __builtin_amdgcn_global_load_lds( \
      (const __attribute__((address_space(1))) u32*)(src), \
      (__attribute__((address_space(3))) u32*)(dst), 16, 0, 0)
#define STAGE(reg, tau) do { \
    int _bo = ((tau) & 1) ? 65536 : 0; \
    GLDS(gsrc[reg][0] + (tau)*64, ldst[reg][0] + _bo); \
    GLDS(gsrc[reg][1] + (tau)*64, ldst[reg][1] + _bo); \
  } while(0)

  // reader constants (byte offsets for asm ds_read)
  int rsel = lane & 15;
  int g4 = lane >> 4;
  int xr = rsel & 7;
  u32 blk0 = (u32)((g4 ^ xr) * 16);            // ks=0 swizzled block (bytes)
  u32 blk1 = (u32)(((4 + g4) ^ xr) * 16);      // ks=1
  u32 aA = lds_off(LDS) + (u32)((wr*128 + rsel)*128);            // A row base
  u32 bB = lds_off(LDS) + 32768u + (u32)((wc*64 + rsel)*128);    // B row base

  int nt = K >> 6;

  f32x4 acc[8][4];
#pragma unroll
  for (int i=0;i<8;i++)
#pragma unroll
    for (int j=0;j<4;j++) acc[i][j] = (f32x4){0.f,0.f,0.f,0.f};

  bf16x8 a0[4], a1[4], b0[4], b1[4];
  auto ldA = [&](bf16x8* a, int mh, u32 blkB, u32 bufo){
#pragma unroll
    for (int m=0;m<4;m++)
      a[m] = dsr(aA + bufo + (u32)((mh*64 + m*16)*128) + blkB);
  };
  auto ldB = [&](bf16x8* bq, u32 blkB, u32 bufo){
#pragma unroll
    for (int n=0;n<4;n++)
      bq[n] = dsr(bB + bufo + (u32)((n*16)*128) + blkB);
  };
  auto mm = [&](bf16x8* a, bf16x8* bq, int mh){
#pragma unroll
    for (int m=0;m<4;m++)
#pragma unroll
      for (int n=0;n<4;n++)
        acc[mh*4+m][n] = __builtin_amdgcn_mfma_f32_16x16x32_bf16(a[m], bq[n], acc[mh*4+m][n], 0, 0, 0);
  };

#define WAITL(N) do { \
    asm volatile("s_waitcnt lgkmcnt(" #N ")" ::: "memory"); \
    __builtin_amdgcn_sched_barrier(0); \
  } while(0)

  // prologue: stage tile0 completely (8 loads/thread in flight)
  STAGE(0,0); STAGE(1,0); STAGE(2,0); STAGE(3,0);

#pragma unroll 1
  for (int t=0; t<nt; ++t){
    u32 bufo = (u32)(t & 1) * 65536u;
    // tile t fully staged (its 8 loads are the only outstanding VMEM)
    asm volatile("s_waitcnt vmcnt(0)" ::: "memory");
    asm volatile("s_barrier" ::: "memory");
    // issue all mh0 reads: a0,b0 first (Q0), then a1,b1 (Q1)
    ldA(a0, 0, blk0, bufo); ldB(b0, blk0, bufo);
    ldA(a1, 0, blk1, bufo); ldB(b1, blk1, bufo);
    // stage ENTIRE next tile into the opposite buffer (no WAR: prior readers
    // of that buffer all passed lgkmcnt(0) before this iteration's barrier)
    if (t+1 < nt){ STAGE(0,t+1); STAGE(1,t+1); STAGE(2,t+1); STAGE(3,t+1); }
    WAITL(8);                              // a0,b0 ready; a1,b1 in flight
    __builtin_amdgcn_s_setprio(1); mm(a0, b0, 0); __builtin_amdgcn_s_setprio(0);
    ldA(a0, 1, blk0, bufo);                // recycle a0 <- (mh1, ks0)
    WAITL(4);                              // a1,b1 ready; a0' in flight
    __builtin_amdgcn_s_setprio(1); mm(a1, b1, 0); __builtin_amdgcn_s_setprio(0);
    ldA(a1, 1, blk1, bufo);                // recycle a1 <- (mh1, ks1)
    WAITL(4);                              // a0' ready; a1' in flight
    __builtin_amdgcn_s_setprio(1); mm(a0, b0, 1); __builtin_amdgcn_s_setprio(0);
    WAITL(0);                              // a1' ready
    __builtin_amdgcn_s_setprio(1); mm(a1, b1, 1); __builtin_amdgcn_s_setprio(0);
  }
#undef WAITL
#undef STAGE
#undef GLDS

  // epilogue: C/D frag layout col=lane&15, row=(lane>>4)*4+j
  int cq = (lane >> 4) * 4;
  int csel = lane & 15;
#pragma unroll
  for (int mi=0; mi<8; mi++){
#pragma unroll
    for (int n=0; n<4; n++){
#pragma unroll
      for (int j=0; j<4; j++){
        int gm = m0 + wr*128 + mi*16 + cq + j;
        int gn = n0 + wc*64 + n*16 + csel;
        if (gm < Mvalid && gn < Nwrite){
          float v = acc[mi][n][j];
          if (BIAS) v += bias[gn];
          if (GELU) v = 0.5f*v*(1.0f + erff(v*0.70710678118654752f));
          if (CMAP == 0){
            C[(long)gm*ldc + gn] = f2bf(v);
          } else if (CMAP == 1){
            int bb = gm / 729;
            int jj = gm - bb*729;
            C[((long)bb*857 + jj)*3072 + gn] = f2bf(v);
          } else {
            if (gn < 1536){
              C[(long)gm*1536 + gn] = f2bf(v * 0.1020620726159657f);
            } else {
              int bb = gm >> 7, jj = gm & 127;
              C2[((long)bb*857 + 729 + jj)*3072 + (gn - 1536)] = f2bf(v);
            }
          }
        }
      }
    }
  }
}

// ---------------------------------------------------------------------------
// 128x128 2-phase GEMM (verified r2) for small/batched shapes.
// ---------------------------------------------------------------------------
template<int GELU, int BIAS, int RES, int OUTF32>
__global__ __launch_bounds__(256)
void gemm_t(const short* __restrict__ A, const short* __restrict__ B,
            void* __restrict__ C, const float* __restrict__ bias,
            const float* __restrict__ res,
            int K, int lda, int ldb, int ldc,
            int Mvalid, int NBmax, int Nwrite,
            int zdiv, long sA1, long sA2, long sB1, long sB2, long sC1, long sC2,
            float scale)
{
  __shared__ __align__(16) short As[2][128*32];
  __shared__ __align__(16) short Bs[2][128*32];

  int z = blockIdx.z;
  int zq = z / zdiv, zr = z - zq*zdiv;
  const short* Ab = A + zq*sA1 + zr*sA2;
  const short* Bb = B + zq*sB1 + zr*sB2;
  long cOff = zq*sC1 + zr*sC2;
  int m0 = blockIdx.y * 128;
  int n0 = blockIdx.x * 128;
  int tid = threadIdx.x;
  int lane = tid & 63;
  int w = tid >> 6;
  int wm = (w >> 1) * 64, wn = (w & 1) * 64;

  int sr = lane >> 2;
  int sc = (lane & 3) * 8;
  int ar0 = m0 + w*32 + sr;
  int br0 = n0 + w*32 + sr;

  int raA0 = ar0;      if (raA0 > Mvalid-1) raA0 = Mvalid-1;
  int raA1 = ar0 + 16; if (raA1 > Mvalid-1) raA1 = Mvalid-1;
  int rbB0 = br0;      if (rbB0 > NBmax-1) rbB0 = NBmax-1;
  int rbB1 = br0 + 16; if (rbB1 > NBmax-1) rbB1 = NBmax-1;
  const short* gA0 = Ab + (long)raA0*lda + sc;
  const short* gA1 = Ab + (long)raA1*lda + sc;
  const short* gB0 = Bb + (long)rbB0*ldb + sc;
  const short* gB1 = Bb + (long)rbB1*ldb + sc;
  int ldsRow0 = (w*32)*32;
  int ldsRow1 = (w*32 + 16)*32;

  f32x4 acc[4][4];
#pragma unroll
  for (int i=0;i<4;i++)
#pragma unroll
    for (int j=0;j<4;j++) acc[i][j] = (f32x4){0.f,0.f,0.f,0.f};

  auto stage = [&](int buf, int kb){
    __builtin_amdgcn_global_load_lds(
        (const __attribute__((address_space(1))) u32*)(gA0 + kb),
        (__attribute__((address_space(3))) u32*)(&As[buf][ldsRow0]), 16, 0, 0);
    __builtin_amdgcn_global_load_lds(
        (const __attribute__((address_space(1))) u32*)(gA1 + kb),
        (__attribute__((address_space(3))) u32*)(&As[buf][ldsRow1]), 16, 0, 0);
    __builtin_amdgcn_global_load_lds(
        (const __attribute__((address_space(1))) u32*)(gB0 + kb),
        (__attribute__((address_space(3))) u32*)(&Bs[buf][ldsRow0]), 16, 0, 0);
    __builtin_amdgcn_global_load_lds(
        (const __attribute__((address_space(1))) u32*)(gB1 + kb),
        (__attribute__((address_space(3))) u32*)(&Bs[buf][ldsRow1]), 16, 0, 0);
  };

  int nt = K >> 5;
  stage(0, 0);
  __syncthreads();

  int kq = (lane >> 4) * 8;
  int rsel = lane & 15;
  int cur = 0;
  for (int t = 0; t < nt; ++t){
    if (t + 1 < nt) stage(cur ^ 1, (t+1)*32);

    bf16x8 af[4], bfr[4];
#pragma unroll
    for (int m=0;m<4;m++) af[m]  = *(const bf16x8*)&As[cur][(wm + m*16 + rsel)*32 + kq];
#pragma unroll
    for (int n=0;n<4;n++) bfr[n] = *(const bf16x8*)&Bs[cur][(wn + n*16 + rsel)*32 + kq];
#pragma unroll
    for (int m=0;m<4;m++)
#pragma unroll
      for (int n=0;n<4;n++)
        acc[m][n] = __builtin_amdgcn_mfma_f32_16x16x32_bf16(af[m], bfr[n], acc[m][n], 0, 0, 0);

    __syncthreads();
    cur ^= 1;
  }

  int cq = (lane >> 4) * 4;
  int csel = lane & 15;
#pragma unroll
  for (int m=0;m<4;m++){
#pragma unroll
    for (int n=0;n<4;n++){
#pragma unroll
      for (int j=0;j<4;j++){
        int gm = m0 + wm + m*16 + cq + j;
        int gn = n0 + wn + n*16 + csel;
        if (gm < Mvalid && gn < Nwrite){
          float v = acc[m][n][j] * scale;
          if (BIAS) v += bias[gn];
          if (GELU) v = 0.5f*v*(1.0f + erff(v*0.70710678118654752f));
          long off = cOff + (long)gm*ldc + gn;
          if (OUTF32){
            float rv = RES ? res[off] : 0.0f;
            ((float*)C)[off] = v + rv;
          } else {
            ((short*)C)[off] = f2bf(v);
          }
        }
      }
    }
  }
}

// ---------------------------------------------------------------------------
__global__ __launch_bounds__(256)
void convT(const float* __restrict__ in, short* __restrict__ out,
           int K, int N, const float* __restrict__ s)
{
  __shared__ float tile[32][33];
  int kb = blockIdx.y*32, nb = blockIdx.x*32;
  int tx = threadIdx.x & 31, ty = threadIdx.x >> 5;
  for (int i = ty; i < 32; i += 8){
    int k = kb + i, n = nb + tx;
    float v = 0.f;
    if (k < K && n < N){ v = in[(long)k*N + n]; if (s) v *= s[k]; }
    tile[i][tx] = v;
  }
  __syncthreads();
  for (int i = ty; i < 32; i += 8){
    int n = nb + i, k = kb + tx;
    if (n < N && k < K) out[(long)n*K + k] = f2bf(tile[tx][i]);
  }
}

__global__ __launch_bounds__(256)
void biasfold(const float* __restrict__ W, const float* __restrict__ bvec, float* __restrict__ outb)
{
  int n = blockIdx.x*256 + threadIdx.x;
  float s = 0.f;
  for (int k=0;k<1152;k++) s += bvec[k]*W[(long)k*3072 + n];
  outb[n] = s;
}

__global__ __launch_bounds__(256)
void cvt_bf16x4(const float* __restrict__ in, short* __restrict__ o, long n)
{
  long i = ((long)blockIdx.x*256 + threadIdx.x)*4;
  if (i >= n) return;
  float4 v = *(const float4*)(in + i);
  o[i+0]=f2bf(v.x); o[i+1]=f2bf(v.y); o[i+2]=f2bf(v.z); o[i+3]=f2bf(v.w);
}

__global__ __launch_bounds__(256)
void latcopy(const float* __restrict__ latents, float* __restrict__ lat)
{
  int idx = blockIdx.x*256 + threadIdx.x;
  int d = idx % 1152; int j = (idx / 1152) % 64; int b = idx / (1152*64);
  lat[((long)b*128 + j)*1152 + d] = latents[j*1152 + d];
}

__global__ __launch_bounds__(256)
void transV(const short* __restrict__ kv, short* __restrict__ Vt)
{
  int b = blockIdx.z;
  __shared__ short tile[32][33];
  int rb = blockIdx.y*32, cb = blockIdx.x*32;
  int tx = threadIdx.x & 31, ty = threadIdx.x >> 5;
  for (int i=ty; i<32; i+=8){
    int r = rb+i, c = cb+tx;
    short v = 0;
    if (r < 857) v = kv[((long)b*857 + r)*3072 + 1536 + c];
    tile[i][tx] = v;
  }
  __syncthreads();
  for (int i=ty;i<32;i+=8){
    int c = cb+i, r = rb+tx;
    Vt[((long)b*1536 + c)*864 + r] = tile[tx][i];
  }
}

__global__ __launch_bounds__(256)
void softmax_rows(short* __restrict__ SP)
{
  long row = (long)blockIdx.x*4 + (threadIdx.x >> 6);
  int lane = threadIdx.x & 63;
  short* p = SP + row*896;
  float vals[14];
  float mx = -1e30f;
#pragma unroll
  for (int i=0;i<14;i++){
    int j = i*64 + lane;
    float v = (j < 857) ? bf2f(p[j]) : -1e30f;
    vals[i] = v; mx = fmaxf(mx, v);
  }
#pragma unroll
  for (int o=32;o;o>>=1) mx = fmaxf(mx, __shfl_xor(mx, o));
  float s = 0.f;
#pragma unroll
  for (int i=0;i<14;i++){
    int j = i*64 + lane;
    float e = (j < 857) ? __expf(vals[i]-mx) : 0.f;
    vals[i] = e; s += e;
  }
#pragma unroll
  for (int o=32;o;o>>=1) s += __shfl_xor(s, o);
  float inv = 1.0f / s;
#pragma unroll
  for (int i=0;i<14;i++){
    int j = i*64 + lane;
    if (j < 864) p[j] = f2bf(j < 857 ? vals[i]*inv : 0.f);
  }
}

template<int OUTF32>
__global__ __launch_bounds__(256)
void ln_k(const float* __restrict__ in, void* __restrict__ outp,
          const float* __restrict__ w, const float* __restrict__ b,
          int grpSel, int grpStride)
{
  const int D = 1152;
  int r = blockIdx.x;
  long ir = (long)(r / grpSel)*grpStride + (r % grpSel);
  const float* x = in + ir*D;
  int tid = threadIdx.x;
  float s1=0.f, s2=0.f;
  float xv[5];
#pragma unroll
  for (int t=0;t<5;t++){
    int i = tid + t*256;
    xv[t] = (i < D) ? x[i] : 0.f;
    s1 += xv[t]; s2 += xv[t]*xv[t];
  }
#pragma unroll
  for (int o=32;o;o>>=1){ s1 += __shfl_xor(s1,o); s2 += __shfl_xor(s2,o); }
  __shared__ float red[8];
  int wid = tid>>6, lane = tid&63;
  if (lane==0){ red[wid]=s1; red[4+wid]=s2; }
  __syncthreads();
  s1 = red[0]+red[1]+red[2]+red[3];
  s2 = red[4]+red[5]+red[6]+red[7];
  float mu = s1 / D;
  float var = s2 / D - mu*mu;
  float rs = rsqrtf(var + 1e-5f);
#pragma unroll
  for (int t=0;t<5;t++){
    int i = tid + t*256;
    if (i >= D) break;
    float v = (xv[t]-mu)*rs;
    if (w) v = v*w[i] + b[i];
    if (OUTF32) ((float*)outp)[(long)r*D + i] = v;
    else        ((short*)outp)[(long)r*D + i] = f2bf(v);
  }
}

// ---------------------------------------------------------------------------

extern "C" void kernel_launch(void* const* d_in, const int* in_sizes, int n_in,
                              void* d_out, int out_size, void* d_ws, size_t ws_size,
                              hipStream_t stream)
{
  const float* x      = (const float*)d_in[0];
  const float* tein   = (const float*)d_in[1];
  const float* lat0   = (const float*)d_in[2];
  const float* txt_w1 = (const float*)d_in[3];
  const float* txt_b1 = (const float*)d_in[4];
  const float* txt_w2 = (const float*)d_in[5];
  const float* txt_b2 = (const float*)d_in[6];
  const float* nm_w   = (const float*)d_in[7];
  const float* nm_b   = (const float*)d_in[8];
  const float* nl_w   = (const float*)d_in[9];
  const float* nl_b   = (const float*)d_in[10];
  const float* Wq     = (const float*)d_in[11];
  const float* Wkv    = (const float*)d_in[12];
  const float* Wo     = (const float*)d_in[13];
  const float* ffln_w = (const float*)d_in[14];
  const float* ffln_b = (const float*)d_in[15];
  const float* ff_w1  = (const float*)d_in[16];
  const float* ff_w2  = (const float*)d_in[17];
  const float* oln_w  = (const float*)d_in[18];
  const float* oln_b  = (const float*)d_in[19];
  float* out = (float*)d_out;
  (void)in_sizes; (void)n_in; (void)out_size; (void)ws_size;

  char* base = (char*)d_ws;
  size_t off = 0;
  auto alloc = [&](size_t bytes)->char*{
    char* r = base + off;
    off += (bytes + 255) & ~(size_t)255;
    return r;
  };
  short* wT    = (short*)alloc(4608ULL*1152*2);
  float* biasf = (float*)alloc(3072*4);
  short* xnorm = (short*)alloc(23328ULL*1152*2);
  float* lat   = (float*)alloc(4096ULL*1152*4);
  short* lm    = (short*)alloc(4096ULL*1152*2);
  short* qb    = (short*)alloc(4096ULL*1536*2);
  short* kv    = (short*)alloc(27424ULL*3072*2);
  short* Vt    = (short*)alloc(32ULL*1536*864*2);
  short* SP    = (short*)alloc(65536ULL*896*2);
  short* attn  = (short*)alloc(4096ULL*1536*2);
  short* ffh   = (short*)alloc(4096ULL*4608*2);
  short* txtin = SP;
  short* txth  = SP + 2048ULL*4096;

  // ---- preamble ----
  cvt_bf16x4<<<8192,256,0,stream>>>(tein, txtin, 2048LL*4096);
  convT<<<dim3(36,128),256,0,stream>>>(txt_w1, wT, 4096, 1152, nullptr);
  gemm_t<1,1,0,0><<<dim3(9,16,1),256,0,stream>>>(txtin, wT, txth, txt_b1, nullptr,
      4096,4096,4096,1152, 2048,1152,1152, 1, 0,0,0,0,0,0, 1.f);
  convT<<<dim3(36,36),256,0,stream>>>(txt_w2, wT, 1152, 1152, nullptr);
  gemm_t<0,1,0,1><<<dim3(9,1,32),256,0,stream>>>(txth, wT, lat + 64*1152, txt_b2, nullptr,
      1152,1152,1152,1152, 64,1152,1152, 1, 64L*1152,0, 0,0, 128L*1152,0, 1.f);
  latcopy<<<9216,256,0,stream>>>(lat0, lat);

  ln_k<0><<<23328,256,0,stream>>>(x, xnorm, nullptr, nullptr, 1<<28, 0);

  for (int L=0; L<6; L++){
    const float* WqL  = Wq    + (size_t)L*1152*1536;
    const float* WkvL = Wkv   + (size_t)L*1152*3072;
    const float* WoL  = Wo    + (size_t)L*1536*1152;
    const float* fw1  = ff_w1 + (size_t)L*1152*4608;
    const float* fw2  = ff_w2 + (size_t)L*4608*1152;

    // lm = LN(lat; nl)
    ln_k<0><<<4096,256,0,stream>>>(lat, lm, nl_w + L*1152, nl_b + L*1152, 1<<28, 0);

    // fused q | kv-latent: wT = [Wq^T (1536 rows) ; Wkv^T (3072 rows)]
    convT<<<dim3(48,36),256,0,stream>>>(WqL, wT, 1152, 1536, nullptr);
    convT<<<dim3(96,36),256,0,stream>>>(WkvL, wT + 1536*1152, 1152, 3072, nullptr);
    gemm256<0,0,2><<<dim3(18,16),512,0,stream>>>(lm, wT, qb, kv, nullptr,
        1152,1152,1152,0, 4096, 4608, 4608);

    // kv x part (folded nm affine)
    convT<<<dim3(96,36),256,0,stream>>>(WkvL, wT, 1152, 3072, nm_w + L*1152);
    biasfold<<<12,256,0,stream>>>(WkvL, nm_b + L*1152, biasf);
    gemm256<0,1,1><<<dim3(12,92),512,0,stream>>>(xnorm, wT, kv, nullptr, biasf,
        1152,1152,1152,0, 23328, 3072, 3072);

    // Vt = V^T per batch
    transV<<<dim3(48,27,32),256,0,stream>>>(kv, Vt);

    // S = q . k^T
    gemm_t<0,0,0,0><<<dim3(7,1,512),256,0,stream>>>(qb, kv, SP, nullptr, nullptr,
        96,1536,3072,896, 128,857,896, 16,
        128L*1536,96, 857L*3072,96, 16L*128*896,128L*896, 1.f);
    softmax_rows<<<16384,256,0,stream>>>(SP);
    gemm_t<0,0,0,0><<<dim3(1,1,512),256,0,stream>>>(SP, Vt, attn, nullptr, nullptr,
        864,896,864,1536, 128,96,96, 16,
        16L*128*896,128L*896, 1536L*864,96L*864, 128L*1536,96, 1.f);

    // lat += attn @ Wo
    convT<<<dim3(36,48),256,0,stream>>>(WoL, wT, 1536, 1152, nullptr);
    gemm_t<0,0,1,1><<<dim3(9,32,1),256,0,stream>>>(attn, wT, lat, nullptr, lat,
        1536,1536,1536,1152, 4096,1152,1152, 1, 0,0,0,0,0,0, 1.f);

    // FF
    ln_k<0><<<4096,256,0,stream>>>(lat, lm, ffln_w + L*1152, ffln_b + L*1152, 1<<28, 0);
    convT<<<dim3(144,36),256,0,stream>>>(fw1, wT, 1152, 4608, nullptr);
    gemm256<1,0,0><<<dim3(18,16),512,0,stream>>>(lm, wT, ffh, nullptr, nullptr,
        1152,1152,1152,4608, 4096,4608,4608);
    convT<<<dim3(36,144),256,0,stream>>>(fw2, wT, 4608, 1152, nullptr);
    gemm_t<0,0,1,1><<<dim3(9,32,1),256,0,stream>>>(ffh, wT, lat, nullptr, lat,
        4608,4608,4608,1152, 4096,1152,1152, 1, 0,0,0,0,0,0, 1.f);
  }

  ln_k<1><<<2048,256,0,stream>>>(lat, out, oln_w, oln_b, 64, 128);
}

// Round 8
// 5294.222 us; speedup vs baseline: 1.1125x; 1.0920x over previous
//
#include <hip/hip_runtime.h>
#include <hip/hip_bf16.h>
#include <math.h>

// InstructPerceiverResampler on MI355X (gfx950).
// Round 8: FLASH ATTENTION kernel replaces S-gemm + softmax_rows + PV-gemm
// (was ~350 MB HBM traffic/layer for 22 GF of math). Swapped QK^T so softmax
// is lane-local; P round-trips LDS in exactly the PV A-frag layout; online
// (m,l) with LDS-broadcast rescale. 512 blocks = 2/CU (67 KB LDS) so two
// blocks overlap each other's stalls (m114). gemm256/gemm_t unchanged (R7).
// Also: convT2 emits plain+scaled Wkv^T in one read pass.

typedef __attribute__((ext_vector_type(4))) float f32x4;
typedef __attribute__((ext_vector_type(8))) short bf16x8;
typedef unsigned int u32;

#define DEV __device__ __forceinline__

DEV float bf2f(short s){ union{u32 u; float f;} v; v.u = ((u32)(unsigned short)s) << 16; return v.f; }
DEV short f2bf(float f){
  union{float f; u32 u;} v; v.f = f;
  u32 r = (v.u + 0x7FFFu + ((v.u >> 16) & 1u)) >> 16;
  return (short)r;
}

DEV u32 lds_off(const short* p){
  return (u32)(uintptr_t)(__attribute__((address_space(3))) const short*)p;
}
DEV bf16x8 dsr(u32 addr){
  bf16x8 r;
  asm volatile("ds_read_b128 %0, %1" : "=v"(r) : "v"(addr));
  return r;
}

// ---------------------------------------------------------------------------
// Flash attention: one block per (b,h). 4 waves x 32 q-rows. 9 KV-tiles of 96.
// S^T = mfma(K, Q)  ->  lane-local softmax  ->  P to LDS (A-frag layout)
// ->  O += P @ V^T-rows, online rescale.
// ---------------------------------------------------------------------------
__global__ __launch_bounds__(256)
void flash_attn(const short* __restrict__ qb, const short* __restrict__ kv,
                const short* __restrict__ Vtg, short* __restrict__ attn)
{
  __shared__ short Kt[96][104];      // [key][d]
  __shared__ short Vs[96][104];      // [d][key]
  __shared__ short Pb[4][32][104];   // per-wave P[q][key]
  __shared__ float FAC[128];         // per-q rescale broadcast

  int z = blockIdx.x;
  int b = z >> 4, h = z & 15;
  int tid = threadIdx.x;
  int lane = tid & 63;
  int w = tid >> 6;
  int l15 = lane & 15, g4 = lane >> 4;

  // Q fragments, held for the whole kernel (B-operand: lane = q-row l15)
  bf16x8 qf[2][3];
#pragma unroll
  for (int n=0;n<2;n++)
#pragma unroll
    for (int kf=0;kf<3;kf++)
      qf[n][kf] = *(const bf16x8*)&qb[((long)(b*128 + w*32 + n*16 + l15))*1536
                                     + h*96 + kf*32 + g4*8];

  f32x4 acc[2][6];
#pragma unroll
  for (int i=0;i<2;i++)
#pragma unroll
    for (int j=0;j<6;j++) acc[i][j] = (f32x4){0.f,0.f,0.f,0.f};
  float m_run[2] = {-1e30f, -1e30f};
  float l_run[2] = {0.f, 0.f};

  const short* kvb = kv  + (long)b*857*3072 + h*96;
  const short* vtb = Vtg + ((long)b*1536 + h*96)*864;

  for (int t=0; t<9; ++t){
    int k0 = t*96;
    // ---- stage K-tile [96 keys][96 d] and V^T-tile [96 d][96 keys] ----
    for (int c = tid; c < 1152; c += 256){
      int r = c / 12;
      int c12 = c - r*12;
      int key = k0 + r; if (key > 856) key = 856;
      *(bf16x8*)&Kt[r][c12*8] = *(const bf16x8*)&kvb[(long)key*3072 + c12*8];
      *(bf16x8*)&Vs[r][c12*8] = *(const bf16x8*)&vtb[(long)r*864 + k0 + c12*8];
    }
    __syncthreads();

    // ---- S^T tile: C[key][q] = sum_d K[key][d] * Q[q][d] ----
    f32x4 st[6][2];
#pragma unroll
    for (int m=0;m<6;m++){ st[m][0]=(f32x4){0,0,0,0}; st[m][1]=(f32x4){0,0,0,0}; }
#pragma unroll
    for (int kf=0;kf<3;kf++){
      bf16x8 af[6];
#pragma unroll
      for (int m=0;m<6;m++) af[m] = *(const bf16x8*)&Kt[m*16 + l15][kf*32 + g4*8];
#pragma unroll
      for (int m=0;m<6;m++){
        st[m][0] = __builtin_amdgcn_mfma_f32_16x16x32_bf16(af[m], qf[0][kf], st[m][0], 0,0,0);
        st[m][1] = __builtin_amdgcn_mfma_f32_16x16x32_bf16(af[m], qf[1][kf], st[m][1], 0,0,0);
      }
    }

    // ---- mask tail keys ----
    if (k0 + 96 > 857){
#pragma unroll
      for (int m=0;m<6;m++)
#pragma unroll
        for (int j=0;j<4;j++){
          if (k0 + m*16 + g4*4 + j > 856){ st[m][0][j] = -1e30f; st[m][1][j] = -1e30f; }
        }
    }

    // ---- lane-local online softmax (q = n*16 + l15; keys over m,j,g4) ----
#pragma unroll
    for (int n=0;n<2;n++){
      float mx = -1e30f;
#pragma unroll
      for (int m=0;m<6;m++)
#pragma unroll
        for (int j=0;j<4;j++) mx = fmaxf(mx, st[m][n][j]);
      mx = fmaxf(mx, __shfl_xor(mx, 16));
      mx = fmaxf(mx, __shfl_xor(mx, 32));
      float mn = fmaxf(m_run[n], mx);
      float f  = __expf(m_run[n] - mn);
      m_run[n] = mn;
      float s = 0.f;
#pragma unroll
      for (int m=0;m<6;m++)
#pragma unroll
        for (int j=0;j<4;j++){
          float e = __expf(st[m][n][j] - mn);
          st[m][n][j] = e; s += e;
        }
      s += __shfl_xor(s, 16);
      s += __shfl_xor(s, 32);
      l_run[n] = l_run[n]*f + s;
      if (g4 == 0) FAC[w*32 + n*16 + l15] = f;
    }

    // ---- P -> LDS in PV A-frag layout: Pb[w][q][key] ----
#pragma unroll
    for (int m=0;m<6;m++)
#pragma unroll
      for (int n=0;n<2;n++){
        short4 pk;
        pk.x = f2bf(st[m][n][0]); pk.y = f2bf(st[m][n][1]);
        pk.z = f2bf(st[m][n][2]); pk.w = f2bf(st[m][n][3]);
        *(short4*)&Pb[w][n*16 + l15][m*16 + g4*4] = pk;
      }

    // ---- rescale O by f (per-q from FAC; wave-local, no barrier) ----
    {
      float4 fj0 = *(const float4*)&FAC[w*32 +  0 + g4*4];
      float4 fj1 = *(const float4*)&FAC[w*32 + 16 + g4*4];
#pragma unroll
      for (int nn=0;nn<6;nn++){
        acc[0][nn][0] *= fj0.x; acc[0][nn][1] *= fj0.y;
        acc[0][nn][2] *= fj0.z; acc[0][nn][3] *= fj0.w;
        acc[1][nn][0] *= fj1.x; acc[1][nn][1] *= fj1.y;
        acc[1][nn][2] *= fj1.z; acc[1][nn][3] *= fj1.w;
      }
    }

    // ---- PV: O[q][d] += P[q][key] * Vt[d][key] ----
#pragma unroll
    for (int kf=0;kf<3;kf++){
      bf16x8 pa0 = *(const bf16x8*)&Pb[w][ 0 + l15][kf*32 + g4*8];
      bf16x8 pa1 = *(const bf16x8*)&Pb[w][16 + l15][kf*32 + g4*8];
#pragma unroll
      for (int nn=0;nn<6;nn++){
        bf16x8 vb = *(const bf16x8*)&Vs[nn*16 + l15][kf*32 + g4*8];
        acc[0][nn] = __builtin_amdgcn_mfma_f32_16x16x32_bf16(pa0, vb, acc[0][nn], 0,0,0);
        acc[1][nn] = __builtin_amdgcn_mfma_f32_16x16x32_bf16(pa1, vb, acc[1][nn], 0,0,0);
      }
    }
    __syncthreads();
  }

  // ---- finalize: divide by l (redistribute via FAC), write attn ----
  if (g4 == 0){
    FAC[w*32 +  0 + l15] = 1.0f / l_run[0];
    FAC[w*32 + 16 + l15] = 1.0f / l_run[1];
  }
  float4 li0 = *(const float4*)&FAC[w*32 +  0 + g4*4];
  float4 li1 = *(const float4*)&FAC[w*32 + 16 + g4*4];
  float li[2][4] = {{li0.x,li0.y,li0.z,li0.w},{li1.x,li1.y,li1.z,li1.w}};
#pragma unroll
  for (int mo=0;mo<2;mo++)
#pragma unroll
    for (int nn=0;nn<6;nn++)
#pragma unroll
      for (int j=0;j<4;j++){
        int q = w*32 + mo*16 + g4*4 + j;
        int d = nn*16 + l15;
        attn[((long)(b*128+q))*1536 + h*96 + d] = f2bf(acc[mo][nn][j]*li[mo][j]);
      }
}

// ---------------------------------------------------------------------------
// 256x256 GEMM (R7 schedule): one barrier + one vmcnt(0) per K-tile.
// ---------------------------------------------------------------------------
template<int GELU, int BIAS, int CMAP>
__global__ __launch_bounds__(512, 2)
void gemm256(const short* __restrict__ A, const short* __restrict__ Bm,
             short* __restrict__ C, short* __restrict__ C2,
             const float* __restrict__ bias,
             int K, int lda, int ldb, int ldc,
             int Mvalid, int NBmax, int Nwrite)
{
  __shared__ __align__(16) short LDS[65536];

  int nwg = gridDim.x * gridDim.y;
  int bid = blockIdx.y * gridDim.x + blockIdx.x;
  if ((nwg & 7) == 0){
    int chunk = nwg >> 3;
    bid = (bid & 7) * chunk + (bid >> 3);
  }
  int by = bid / gridDim.x;
  int m0 = by * 256;
  int n0 = (bid - by * gridDim.x) * 256;

  int tid = threadIdx.x;
  int lane = tid & 63;
  int w = tid >> 6;
  int wr = w >> 2, wc = w & 3;

  int sl = lane >> 3;
  int scol = ((lane & 7) ^ sl) * 8;

  const short* gsrc[4][2];
  {
    int rb = n0 + w*8 + sl;
    int ra = m0 + w*8 + sl;
    int rows[4][2] = {{rb, rb+64},{rb+128, rb+192},{ra, ra+64},{ra+128, ra+192}};
#pragma unroll
    for (int r=0;r<4;r++){
#pragma unroll
      for (int c2=0;c2<2;c2++){
        int rr = rows[r][c2];
        int lim = (r < 2) ? (NBmax-1) : (Mvalid-1);
        if (rr > lim) rr = lim;
        const short* bp = (r < 2) ? Bm : A;
        int ld = (r < 2) ? ldb : lda;
        gsrc[r][c2] = bp + (long)rr*ld + scol;
      }
    }
  }
  char* ldst[4][2];
#pragma unroll
  for (int r=0;r<4;r++){
    int sbase = ((r & 2) ? 0 : 16384) + (r & 1)*8192;
    ldst[r][0] = (char*)LDS + (sbase + (w*8)*64)*2;
    ldst[r][1] = (char*)LDS + (sbase + (64 + w*8)*64)*2;
  }

#define GLDS(src, dst) __builtin_amdgcn_global_load_lds( \
      (const __attribute__((address_space(1))) u32*)(src), \
      (__attribute__((address_space(3))) u32*)(dst), 16, 0, 0)
#define STAGE(reg, tau) do { \
    int _bo = ((tau) & 1) ? 65536 : 0; \
    GLDS(gsrc[reg][0] + (tau)*64, ldst[reg][0] + _bo); \
    GLDS(gsrc[reg][1] + (tau)*64, ldst[reg][1] + _bo); \
  } while(0)

  int rsel = lane & 15;
  int g4 = lane >> 4;
  int xr = rsel & 7;
  u32 blk0 = (u32)((g4 ^ xr) * 16);
  u32 blk1 = (u32)(((4 + g4) ^ xr) * 16);
  u32 aA = lds_off(LDS) + (u32)((wr*128 + rsel)*128);
  u32 bB = lds_off(LDS) + 32768u + (u32)((wc*64 + rsel)*128);

  int nt = K >> 6;

  f32x4 acc[8][4];
#pragma unroll
  for (int i=0;i<8;i++)
#pragma unroll
    for (int j=0;j<4;j++) acc[i][j] = (f32x4){0.f,0.f,0.f,0.f};

  bf16x8 a0[4], a1[4], b0[4], b1[4];
  auto ldA = [&](bf16x8* a, int mh, u32 blkB, u32 bufo){
#pragma unroll
    for (int m=0;m<4;m++)
      a[m] = dsr(aA + bufo + (u32)((mh*64 + m*16)*128) + blkB);
  };
  auto ldB = [&](bf16x8* bq, u32 blkB, u32 bufo){
#pragma unroll
    for (int n=0;n<4;n++)
      bq[n] = dsr(bB + bufo + (u32)((n*16)*128) + blkB);
  };
  auto mm = [&](bf16x8* a, bf16x8* bq, int mh){
#pragma unroll
    for (int m=0;m<4;m++)
#pragma unroll
      for (int n=0;n<4;n++)
        acc[mh*4+m][n] = __builtin_amdgcn_mfma_f32_16x16x32_bf16(a[m], bq[n], acc[mh*4+m][n], 0, 0, 0);
  };

#define WAITL(N) do { \
    asm volatile("s_waitcnt lgkmcnt(" #N ")" ::: "memory"); \
    __builtin_amdgcn_sched_barrier(0); \
  } while(0)

  STAGE(0,0); STAGE(1,0); STAGE(2,0); STAGE(3,0);

#pragma unroll 1
  for (int t=0; t<nt; ++t){
    u32 bufo = (u32)(t & 1) * 65536u;
    asm volatile("s_waitcnt vmcnt(0)" ::: "memory");
    asm volatile("s_barrier" ::: "memory");
    ldA(a0, 0, blk0, bufo); ldB(b0, blk0, bufo);
    ldA(a1, 0, blk1, bufo); ldB(b1, blk1, bufo);
    if (t+1 < nt){ STAGE(0,t+1); STAGE(1,t+1); STAGE(2,t+1); STAGE(3,t+1); }
    WAITL(8);
    __builtin_amdgcn_s_setprio(1); mm(a0, b0, 0); __builtin_amdgcn_s_setprio(0);
    ldA(a0, 1, blk0, bufo);
    WAITL(4);
    __builtin_amdgcn_s_setprio(1); mm(a1, b1, 0); __builtin_amdgcn_s_setprio(0);
    ldA(a1, 1, blk1, bufo);
    WAITL(4);
    __builtin_amdgcn_s_setprio(1); mm(a0, b0, 1); __builtin_amdgcn_s_setprio(0);
    WAITL(0);
    __builtin_amdgcn_s_setprio(1); mm(a1, b1, 1); __builtin_amdgcn_s_setprio(0);
  }
#undef WAITL
#undef STAGE
#undef GLDS

  int cq = (lane >> 4) * 4;
  int csel = lane & 15;
#pragma unroll
  for (int mi=0; mi<8; mi++){
#pragma unroll
    for (int n=0; n<4; n++){
#pragma unroll
      for (int j=0; j<4; j++){
        int gm = m0 + wr*128 + mi*16 + cq + j;
        int gn = n0 + wc*64 + n*16 + csel;
        if (gm < Mvalid && gn < Nwrite){
          float v = acc[mi][n][j];
          if (BIAS) v += bias[gn];
          if (GELU) v = 0.5f*v*(1.0f + erff(v*0.70710678118654752f));
          if (CMAP == 0){
            C[(long)gm*ldc + gn] = f2bf(v);
          } else if (CMAP == 1){
            int bb = gm / 729;
            int jj = gm - bb*729;
            C[((long)bb*857 + jj)*3072 + gn] = f2bf(v);
          } else {
            if (gn < 1536){
              C[(long)gm*1536 + gn] = f2bf(v * 0.1020620726159657f);
            } else {
              int bb = gm >> 7, jj = gm & 127;
              C2[((long)bb*857 + 729 + jj)*3072 + (gn - 1536)] = f2bf(v);
            }
          }
        }
      }
    }
  }
}

// ---------------------------------------------------------------------------
// 128x128 2-phase GEMM (verified r2) for small/batched shapes.
// ---------------------------------------------------------------------------
template<int GELU, int BIAS, int RES, int OUTF32>
__global__ __launch_bounds__(256)
void gemm_t(const short* __restrict__ A, const short* __restrict__ B,
            void* __restrict__ C, const float* __restrict__ bias,
            const float* __restrict__ res,
            int K, int lda, int ldb, int ldc,
            int Mvalid, int NBmax, int Nwrite,
            int zdiv, long sA1, long sA2, long sB1, long sB2, long sC1, long sC2,
            float scale)
{
  __shared__ __align__(16) short As[2][128*32];
  __shared__ __align__(16) short Bs[2][128*32];

  int z = blockIdx.z;
  int zq = z / zdiv, zr = z - zq*zdiv;
  const short* Ab = A + zq*sA1 + zr*sA2;
  const short* Bb = B + zq*sB1 + zr*sB2;
  long cOff = zq*sC1 + zr*sC2;
  int m0 = blockIdx.y * 128;
  int n0 = blockIdx.x * 128;
  int tid = threadIdx.x;
  int lane = tid & 63;
  int w = tid >> 6;
  int wm = (w >> 1) * 64, wn = (w & 1) * 64;

  int sr = lane >> 2;
  int sc = (lane & 3) * 8;
  int ar0 = m0 + w*32 + sr;
  int br0 = n0 + w*32 + sr;

  int raA0 = ar0;      if (raA0 > Mvalid-1) raA0 = Mvalid-1;
  int raA1 = ar0 + 16; if (raA1 > Mvalid-1) raA1 = Mvalid-1;
  int rbB0 = br0;      if (rbB0 > NBmax-1) rbB0 = NBmax-1;
  int rbB1 = br0 + 16; if (rbB1 > NBmax-1) rbB1 = NBmax-1;
  const short* gA0 = Ab + (long)raA0*lda + sc;
  const short* gA1 = Ab + (long)raA1*lda + sc;
  const short* gB0 = Bb + (long)rbB0*ldb + sc;
  const short* gB1 = Bb + (long)rbB1*ldb + sc;
  int ldsRow0 = (w*32)*32;
  int ldsRow1 = (w*32 + 16)*32;

  f32x4 acc[4][4];
#pragma unroll
  for (int i=0;i<4;i++)
#pragma unroll
    for (int j=0;j<4;j++) acc[i][j] = (f32x4){0.f,0.f,0.f,0.f};

  auto stage = [&](int buf, int kb){
    __builtin_amdgcn_global_load_lds(
        (const __attribute__((address_space(1))) u32*)(gA0 + kb),
        (__attribute__((address_space(3))) u32*)(&As[buf][ldsRow0]), 16, 0, 0);
    __builtin_amdgcn_global_load_lds(
        (const __attribute__((address_space(1))) u32*)(gA1 + kb),
        (__attribute__((address_space(3))) u32*)(&As[buf][ldsRow1]), 16, 0, 0);
    __builtin_amdgcn_global_load_lds(
        (const __attribute__((address_space(1))) u32*)(gB0 + kb),
        (__attribute__((address_space(3))) u32*)(&Bs[buf][ldsRow0]), 16, 0, 0);
    __builtin_amdgcn_global_load_lds(
        (const __attribute__((address_space(1))) u32*)(gB1 + kb),
        (__attribute__((address_space(3))) u32*)(&Bs[buf][ldsRow1]), 16, 0, 0);
  };

  int nt = K >> 5;
  stage(0, 0);
  __syncthreads();

  int kq = (lane >> 4) * 8;
  int rsel = lane & 15;
  int cur = 0;
  for (int t = 0; t < nt; ++t){
    if (t + 1 < nt) stage(cur ^ 1, (t+1)*32);

    bf16x8 af[4], bfr[4];
#pragma unroll
    for (int m=0;m<4;m++) af[m]  = *(const bf16x8*)&As[cur][(wm + m*16 + rsel)*32 + kq];
#pragma unroll
    for (int n=0;n<4;n++) bfr[n] = *(const bf16x8*)&Bs[cur][(wn + n*16 + rsel)*32 + kq];
#pragma unroll
    for (int m=0;m<4;m++)
#pragma unroll
      for (int n=0;n<4;n++)
        acc[m][n] = __builtin_amdgcn_mfma_f32_16x16x32_bf16(af[m], bfr[n], acc[m][n], 0, 0, 0);

    __syncthreads();
    cur ^= 1;
  }

  int cq = (lane >> 4) * 4;
  int csel = lane & 15;
#pragma unroll
  for (int m=0;m<4;m++){
#pragma unroll
    for (int n=0;n<4;n++){
#pragma unroll
      for (int j=0;j<4;j++){
        int gm = m0 + wm + m*16 + cq + j;
        int gn = n0 + wn + n*16 + csel;
        if (gm < Mvalid && gn < Nwrite){
          float v = acc[m][n][j] * scale;
          if (BIAS) v += bias[gn];
          if (GELU) v = 0.5f*v*(1.0f + erff(v*0.70710678118654752f));
          long off = cOff + (long)gm*ldc + gn;
          if (OUTF32){
            float rv = RES ? res[off] : 0.0f;
            ((float*)C)[off] = v + rv;
          } else {
            ((short*)C)[off] = f2bf(v);
          }
        }
      }
    }
  }
}

// ---------------------------------------------------------------------------
__global__ __launch_bounds__(256)
void convT(const float* __restrict__ in, short* __restrict__ out,
           int K, int N, const float* __restrict__ s)
{
  __shared__ float tile[32][33];
  int kb = blockIdx.y*32, nb = blockIdx.x*32;
  int tx = threadIdx.x & 31, ty = threadIdx.x >> 5;
  for (int i = ty; i < 32; i += 8){
    int k = kb + i, n = nb + tx;
    float v = 0.f;
    if (k < K && n < N){ v = in[(long)k*N + n]; if (s) v *= s[k]; }
    tile[i][tx] = v;
  }
  __syncthreads();
  for (int i = ty; i < 32; i += 8){
    int n = nb + i, k = kb + tx;
    if (n < N && k < K) out[(long)n*K + k] = f2bf(tile[tx][i]);
  }
}

// dual-output transpose: out1 = scaled by s[k], out2 = plain (one read pass)
__global__ __launch_bounds__(256)
void convT2(const float* __restrict__ in, short* __restrict__ out1,
            short* __restrict__ out2, int K, int N, const float* __restrict__ s)
{
  __shared__ float tile[32][33];
  __shared__ float sv[32];
  int kb = blockIdx.y*32, nb = blockIdx.x*32;
  int tx = threadIdx.x & 31, ty = threadIdx.x >> 5;
  if (threadIdx.x < 32){
    int k = kb + threadIdx.x;
    sv[threadIdx.x] = (k < K) ? s[k] : 0.f;
  }
  for (int i = ty; i < 32; i += 8){
    int k = kb + i, n = nb + tx;
    float v = 0.f;
    if (k < K && n < N) v = in[(long)k*N + n];
    tile[i][tx] = v;
  }
  __syncthreads();
  for (int i = ty; i < 32; i += 8){
    int n = nb + i, k = kb + tx;
    if (n < N && k < K){
      float v = tile[tx][i];
      out2[(long)n*K + k] = f2bf(v);
      out1[(long)n*K + k] = f2bf(v * sv[tx]);
    }
  }
}

__global__ __launch_bounds__(256)
void biasfold(const float* __restrict__ W, const float* __restrict__ bvec, float* __restrict__ outb)
{
  int n = blockIdx.x*256 + threadIdx.x;
  float s = 0.f;
  for (int k=0;k<1152;k++) s += bvec[k]*W[(long)k*3072 + n];
  outb[n] = s;
}

__global__ __launch_bounds__(256)
void cvt_bf16x4(const float* __restrict__ in, short* __restrict__ o, long n)
{
  long i = ((long)blockIdx.x*256 + threadIdx.x)*4;
  if (i >= n) return;
  float4 v = *(const float4*)(in + i);
  o[i+0]=f2bf(v.x); o[i+1]=f2bf(v.y); o[i+2]=f2bf(v.z); o[i+3]=f2bf(v.w);
}

__global__ __launch_bounds__(256)
void latcopy(const float* __restrict__ latents, float* __restrict__ lat)
{
  int idx = blockIdx.x*256 + threadIdx.x;
  int d = idx % 1152; int j = (idx / 1152) % 64; int b = idx / (1152*64);
  lat[((long)b*128 + j)*1152 + d] = latents[j*1152 + d];
}

__global__ __launch_bounds__(256)
void transV(const short* __restrict__ kv, short* __restrict__ Vt)
{
  int b = blockIdx.z;
  __shared__ short tile[32][33];
  int rb = blockIdx.y*32, cb = blockIdx.x*32;
  int tx = threadIdx.x & 31, ty = threadIdx.x >> 5;
  for (int i=ty; i<32; i+=8){
    int r = rb+i, c = cb+tx;
    short v = 0;
    if (r < 857) v = kv[((long)b*857 + r)*3072 + 1536 + c];
    tile[i][tx] = v;
  }
  __syncthreads();
  for (int i=ty;i<32;i+=8){
    int c = cb+i, r = rb+tx;
    Vt[((long)b*1536 + c)*864 + r] = tile[tx][i];
  }
}

template<int OUTF32>
__global__ __launch_bounds__(256)
void ln_k(const float* __restrict__ in, void* __restrict__ outp,
          const float* __restrict__ w, const float* __restrict__ b,
          int grpSel, int grpStride)
{
  const int D = 1152;
  int r = blockIdx.x;
  long ir = (long)(r / grpSel)*grpStride + (r % grpSel);
  const float* x = in + ir*D;
  int tid = threadIdx.x;
  float s1=0.f, s2=0.f;
  float xv[5];
#pragma unroll
  for (int t=0;t<5;t++){
    int i = tid + t*256;
    xv[t] = (i < D) ? x[i] : 0.f;
    s1 += xv[t]; s2 += xv[t]*xv[t];
  }
#pragma unroll
  for (int o=32;o;o>>=1){ s1 += __shfl_xor(s1,o); s2 += __shfl_xor(s2,o); }
  __shared__ float red[8];
  int wid = tid>>6, lane = tid&63;
  if (lane==0){ red[wid]=s1; red[4+wid]=s2; }
  __syncthreads();
  s1 = red[0]+red[1]+red[2]+red[3];
  s2 = red[4]+red[5]+red[6]+red[7];
  float mu = s1 / D;
  float var = s2 / D - mu*mu;
  float rs = rsqrtf(var + 1e-5f);
#pragma unroll
  for (int t=0;t<5;t++){
    int i = tid + t*256;
    if (i >= D) break;
    float v = (xv[t]-mu)*rs;
    if (w) v = v*w[i] + b[i];
    if (OUTF32) ((float*)outp)[(long)r*D + i] = v;
    else        ((short*)outp)[(long)r*D + i] = f2bf(v);
  }
}

// ---------------------------------------------------------------------------

extern "C" void kernel_launch(void* const* d_in, const int* in_sizes, int n_in,
                              void* d_out, int out_size, void* d_ws, size_t ws_size,
                              hipStream_t stream)
{
  const float* x      = (const float*)d_in[0];
  const float* tein   = (const float*)d_in[1];
  const float* lat0   = (const float*)d_in[2];
  const float* txt_w1 = (const float*)d_in[3];
  const float* txt_b1 = (const float*)d_in[4];
  const float* txt_w2 = (const float*)d_in[5];
  const float* txt_b2 = (const float*)d_in[6];
  const float* nm_w   = (const float*)d_in[7];
  const float* nm_b   = (const float*)d_in[8];
  const float* nl_w   = (const float*)d_in[9];
  const float* nl_b   = (const float*)d_in[10];
  const float* Wq     = (const float*)d_in[11];
  const float* Wkv    = (const float*)d_in[12];
  const float* Wo     = (const float*)d_in[13];
  const float* ffln_w = (const float*)d_in[14];
  const float* ffln_b = (const float*)d_in[15];
  const float* ff_w1  = (const float*)d_in[16];
  const float* ff_w2  = (const float*)d_in[17];
  const float* oln_w  = (const float*)d_in[18];
  const float* oln_b  = (const float*)d_in[19];
  float* out = (float*)d_out;
  (void)in_sizes; (void)n_in; (void)out_size; (void)ws_size;

  char* base = (char*)d_ws;
  size_t off = 0;
  auto alloc = [&](size_t bytes)->char*{
    char* r = base + off;
    off += (bytes + 255) & ~(size_t)255;
    return r;
  };
  short* wT    = (short*)alloc(4608ULL*1152*2);
  short* wTx   = (short*)alloc(3072ULL*1152*2);   // nm-scaled Wkv^T
  float* biasf = (float*)alloc(3072*4);
  short* xnorm = (short*)alloc(23328ULL*1152*2);
  float* lat   = (float*)alloc(4096ULL*1152*4);
  short* lm    = (short*)alloc(4096ULL*1152*2);
  short* qb    = (short*)alloc(4096ULL*1536*2);
  short* kv    = (short*)alloc(27424ULL*3072*2);
  short* Vt    = (short*)alloc(32ULL*1536*864*2);
  short* SP    = (short*)alloc(2048ULL*4096*2 + 2048ULL*1152*2);  // preamble scratch
  short* attn  = (short*)alloc(4096ULL*1536*2);
  short* ffh   = (short*)alloc(4096ULL*4608*2);
  short* txtin = SP;
  short* txth  = SP + 2048ULL*4096;

  // ---- preamble ----
  cvt_bf16x4<<<8192,256,0,stream>>>(tein, txtin, 2048LL*4096);
  convT<<<dim3(36,128),256,0,stream>>>(txt_w1, wT, 4096, 1152, nullptr);
  gemm_t<1,1,0,0><<<dim3(9,16,1),256,0,stream>>>(txtin, wT, txth, txt_b1, nullptr,
      4096,4096,4096,1152, 2048,1152,1152, 1, 0,0,0,0,0,0, 1.f);
  convT<<<dim3(36,36),256,0,stream>>>(txt_w2, wT, 1152, 1152, nullptr);
  gemm_t<0,1,0,1><<<dim3(9,1,32),256,0,stream>>>(txth, wT, lat + 64*1152, txt_b2, nullptr,
      1152,1152,1152,1152, 64,1152,1152, 1, 64L*1152,0, 0,0, 128L*1152,0, 1.f);
  latcopy<<<9216,256,0,stream>>>(lat0, lat);

  ln_k<0><<<23328,256,0,stream>>>(x, xnorm, nullptr, nullptr, 1<<28, 0);

  for (int L=0; L<6; L++){
    const float* WqL  = Wq    + (size_t)L*1152*1536;
    const float* WkvL = Wkv   + (size_t)L*1152*3072;
    const float* WoL  = Wo    + (size_t)L*1536*1152;
    const float* fw1  = ff_w1 + (size_t)L*1152*4608;
    const float* fw2  = ff_w2 + (size_t)L*4608*1152;

    // lm = LN(lat; nl)
    ln_k<0><<<4096,256,0,stream>>>(lat, lm, nl_w + L*1152, nl_b + L*1152, 1<<28, 0);

    // weight transposes: Wq^T -> wT[0:1536), Wkv^T plain -> wT[1536:4608),
    // Wkv^T nm-scaled -> wTx  (one read pass via convT2)
    convT<<<dim3(48,36),256,0,stream>>>(WqL, wT, 1152, 1536, nullptr);
    convT2<<<dim3(96,36),256,0,stream>>>(WkvL, wTx, wT + 1536*1152, 1152, 3072, nm_w + L*1152);

    // fused q | kv-latent
    gemm256<0,0,2><<<dim3(18,16),512,0,stream>>>(lm, wT, qb, kv, nullptr,
        1152,1152,1152,0, 4096, 4608, 4608);

    // kv x part (folded nm affine)
    biasfold<<<12,256,0,stream>>>(WkvL, nm_b + L*1152, biasf);
    gemm256<0,1,1><<<dim3(12,92),512,0,stream>>>(xnorm, wTx, kv, nullptr, biasf,
        1152,1152,1152,0, 23328, 3072, 3072);

    // Vt = V^T per batch (zero-padded to 864 keys)
    transV<<<dim3(48,27,32),256,0,stream>>>(kv, Vt);

    // fused flash attention: qb,kv,Vt -> attn
    flash_attn<<<512,256,0,stream>>>(qb, kv, Vt, attn);

    // lat += attn @ Wo
    convT<<<dim3(36,48),256,0,stream>>>(WoL, wT, 1536, 1152, nullptr);
    gemm_t<0,0,1,1><<<dim3(9,32,1),256,0,stream>>>(attn, wT, lat, nullptr, lat,
        1536,1536,1536,1152, 4096,1152,1152, 1, 0,0,0,0,0,0, 1.f);

    // FF
    ln_k<0><<<4096,256,0,stream>>>(lat, lm, ffln_w + L*1152, ffln_b + L*1152, 1<<28, 0);
    convT<<<dim3(144,36),256,0,stream>>>(fw1, wT, 1152, 4608, nullptr);
    gemm256<1,0,0><<<dim3(18,16),512,0,stream>>>(lm, wT, ffh, nullptr, nullptr,
        1152,1152,1152,4608, 4096,4608,4608);
    convT<<<dim3(36,144),256,0,stream>>>(fw2, wT, 4608, 1152, nullptr);
    gemm_t<0,0,1,1><<<dim3(9,32,1),256,0,stream>>>(ffh, wT, lat, nullptr, lat,
        4608,4608,4608,1152, 4096,1152,1152, 1, 0,0,0,0,0,0, 1.f);
  }

  ln_k<1><<<2048,256,0,stream>>>(lat, out, oln_w, oln_b, 64, 128);
}

// Round 9
// 4816.484 us; speedup vs baseline: 1.2228x; 1.0992x over previous
//
#include <hip/hip_runtime.h>
#include <hip/hip_bf16.h>
#include <math.h>

// InstructPerceiverResampler on MI355X (gfx950).
// Round 9: gemm_v2 = 128x256 tile, BK=32, 48 KiB LDS, VGPR<=128 -> 2 blocks/CU
// so inter-block TLP (m114) fills the stage/barrier stalls that 4 rounds of
// within-block scheduling could not. Frag offsets as ds_read immediates.
// flash_attn (R8) and small-shape gemm_t unchanged.

typedef __attribute__((ext_vector_type(4))) float f32x4;
typedef __attribute__((ext_vector_type(8))) short bf16x8;
typedef unsigned int u32;

#define DEV __device__ __forceinline__

DEV float bf2f(short s){ union{u32 u; float f;} v; v.u = ((u32)(unsigned short)s) << 16; return v.f; }
DEV short f2bf(float f){
  union{float f; u32 u;} v; v.f = f;
  u32 r = (v.u + 0x7FFFu + ((v.u >> 16) & 1u)) >> 16;
  return (short)r;
}

DEV u32 lds_off(const short* p){
  return (u32)(uintptr_t)(__attribute__((address_space(3))) const short*)p;
}
template<int OFF>
DEV bf16x8 dsro(u32 addr){
  bf16x8 r;
  asm volatile("ds_read_b128 %0, %1 offset:%2" : "=v"(r) : "v"(addr), "i"(OFF));
  return r;
}

// ---------------------------------------------------------------------------
// gemm_v2: C[m,n] = A[m,k]*B[n,k] (+bias)(+gelu)(+res), tiles 128x256, BK=32.
// 512 thr / 8 waves (2 x 4 of 64x64), LDS 2 x (A 8KB | B 16KB) = 48 KiB.
// A[128][32],B[256][32] stored folded as phys[rows/2][64] so the 8-block XOR
// swizzle (phys_blk = logical ^ (row&7)) applies; gload_lds dest stays linear.
// CMAP 0: C[gm*ldc+gn] (short or float per OUTF32)
// CMAP 1: (kv x-part)  C[(gm/729*857 + gm%729)*3072 + gn]
// CMAP 2: (fused q|kv) gn<1536 -> C[gm*1536+gn]*SCALE ; else
//                      C2[((gm>>7)*857+729+(gm&127))*3072 + gn-1536]
// ---------------------------------------------------------------------------
template<int GELU, int BIAS, int RES, int OUTF32, int CMAP>
__global__ __launch_bounds__(512, 4)
void gemm_v2(const short* __restrict__ A, const short* __restrict__ Bm,
             void* __restrict__ Cv, short* __restrict__ C2,
             const float* __restrict__ bias, const float* __restrict__ res,
             int K, int lda, int ldb, int ldc,
             int Mvalid, int NBmax, int Nwrite)
{
  __shared__ __align__(16) short LDS[24576];   // 48 KiB: 2 bufs x (A 8KB | B 16KB)

  int nwg = gridDim.x * gridDim.y;
  int bid = blockIdx.y * gridDim.x + blockIdx.x;
  if ((nwg & 7) == 0){ int chunk = nwg >> 3; bid = (bid & 7)*chunk + (bid >> 3); }
  int by = bid / gridDim.x;
  int m0 = by * 128;
  int n0 = (bid - by*gridDim.x) * 256;

  int tid = threadIdx.x, lane = tid & 63, w = tid >> 6;
  int wr = w >> 2, wc = w & 3;          // wave -> (2 x 4) of 64x64 outputs
  int rsel = lane & 15, g4 = lane >> 4;

  // ---- staging source pointers (loop-invariant) ----
  // dest: phys row = w*8 + sl, phys 16B-block = lane&7; logical = phys ^ sl.
  int sl = lane >> 3;
  int l  = (lane & 7) ^ sl;             // logical block 0..7
  int lc = (l & 3) * 8;                 // source col (shorts)
  int lh = l >> 2;                      // source half
  const short* gA;
  { int r = m0 + w*8 + sl + lh*64; if (r > Mvalid-1) r = Mvalid-1;
    gA = A + (long)r*lda + lc; }
  const short* gB0;
  { int r = n0 + w*8 + sl + lh*128; if (r > NBmax-1) r = NBmax-1;
    gB0 = Bm + (long)r*ldb + lc; }
  const short* gB1;
  { int r = n0 + 64 + w*8 + sl + lh*128; if (r > NBmax-1) r = NBmax-1;
    gB1 = Bm + (long)r*ldb + lc; }
  char* dA  = (char*)LDS + w*1024;
  char* dB0 = (char*)LDS + 8192  + w*1024;
  char* dB1 = (char*)LDS + 16384 + w*1024;

#define GLDS(src, dst) __builtin_amdgcn_global_load_lds( \
      (const __attribute__((address_space(1))) u32*)(src), \
      (__attribute__((address_space(3))) u32*)(dst), 16, 0, 0)
#define STAGE(bo, tau) do { \
    int kb = (tau)*32; \
    GLDS(gA  + kb, dA  + (bo)); \
    GLDS(gB0 + kb, dB0 + (bo)); \
    GLDS(gB1 + kb, dB1 + (bo)); \
  } while(0)

  // ---- reader base addrs (bytes); frag offsets are instruction immediates ----
  u32 base = lds_off(LDS);
  u32 aAddr = base + (u32)(rsel*128 + (((wr*4 + g4) ^ (rsel & 7))*16));
  u32 bAddr = base + 8192u
            + (u32)(((wc & 1)*64 + rsel)*128 + ((((wc >> 1)*4 + g4) ^ (rsel & 7))*16));

  int nt = K >> 5;

  f32x4 acc[4][4];
#pragma unroll
  for (int i=0;i<4;i++)
#pragma unroll
    for (int j=0;j<4;j++) acc[i][j] = (f32x4){0.f,0.f,0.f,0.f};

  STAGE(0u, 0);

#pragma unroll 1
  for (int t=0; t<nt; ++t){
    u32 bo = (t & 1) ? 24576u : 0u;
    asm volatile("s_waitcnt vmcnt(0)" ::: "memory");
    asm volatile("s_barrier" ::: "memory");
    u32 aa = aAddr + bo, bb = bAddr + bo;
    bf16x8 af[4], bfr[4];
    af[0]  = dsro<0>(aa);   af[1]  = dsro<2048>(aa);
    af[2]  = dsro<4096>(aa); af[3] = dsro<6144>(aa);
    bfr[0] = dsro<0>(bb);   bfr[1] = dsro<2048>(bb);
    bfr[2] = dsro<4096>(bb); bfr[3] = dsro<6144>(bb);
    if (t+1 < nt) STAGE(bo ^ 24576u, t+1);
    asm volatile("s_waitcnt lgkmcnt(0)" ::: "memory");
    __builtin_amdgcn_sched_barrier(0);
    __builtin_amdgcn_s_setprio(1);
#pragma unroll
    for (int mi=0; mi<4; mi++)
#pragma unroll
      for (int nn=0; nn<4; nn++)
        acc[mi][nn] = __builtin_amdgcn_mfma_f32_16x16x32_bf16(af[mi], bfr[nn], acc[mi][nn], 0, 0, 0);
    __builtin_amdgcn_s_setprio(0);
  }
#undef STAGE
#undef GLDS

  // ---- epilogue: C/D frag layout col=lane&15, row=(lane>>4)*4+j ----
  int cq = g4 * 4;
  int csel = rsel;
#pragma unroll
  for (int mi=0; mi<4; mi++){
#pragma unroll
    for (int nn=0; nn<4; nn++){
#pragma unroll
      for (int j=0; j<4; j++){
        int gm = m0 + wr*64 + mi*16 + cq + j;
        int gn = n0 + wc*64 + nn*16 + csel;
        if (gm < Mvalid && gn < Nwrite){
          float v = acc[mi][nn][j];
          if (BIAS) v += bias[gn];
          if (GELU) v = 0.5f*v*(1.0f + erff(v*0.70710678118654752f));
          if (CMAP == 0){
            long off = (long)gm*ldc + gn;
            if (OUTF32){
              float rv = RES ? res[off] : 0.0f;
              ((float*)Cv)[off] = v + rv;
            } else {
              ((short*)Cv)[off] = f2bf(v);
            }
          } else if (CMAP == 1){
            int bb2 = gm / 729;
            int jj = gm - bb2*729;
            ((short*)Cv)[((long)bb2*857 + jj)*3072 + gn] = f2bf(v);
          } else {
            if (gn < 1536){
              ((short*)Cv)[(long)gm*1536 + gn] = f2bf(v * 0.1020620726159657f);
            } else {
              int bb2 = gm >> 7, jj = gm & 127;
              C2[((long)bb2*857 + 729 + jj)*3072 + (gn - 1536)] = f2bf(v);
            }
          }
        }
      }
    }
  }
}

// ---------------------------------------------------------------------------
// Flash attention (R8, verified): one block per (b,h). 4 waves x 32 q-rows.
// ---------------------------------------------------------------------------
__global__ __launch_bounds__(256)
void flash_attn(const short* __restrict__ qb, const short* __restrict__ kv,
                const short* __restrict__ Vtg, short* __restrict__ attn)
{
  __shared__ short Kt[96][104];
  __shared__ short Vs[96][104];
  __shared__ short Pb[4][32][104];
  __shared__ float FAC[128];

  int z = blockIdx.x;
  int b = z >> 4, h = z & 15;
  int tid = threadIdx.x;
  int lane = tid & 63;
  int w = tid >> 6;
  int l15 = lane & 15, g4 = lane >> 4;

  bf16x8 qf[2][3];
#pragma unroll
  for (int n=0;n<2;n++)
#pragma unroll
    for (int kf=0;kf<3;kf++)
      qf[n][kf] = *(const bf16x8*)&qb[((long)(b*128 + w*32 + n*16 + l15))*1536
                                     + h*96 + kf*32 + g4*8];

  f32x4 acc[2][6];
#pragma unroll
  for (int i=0;i<2;i++)
#pragma unroll
    for (int j=0;j<6;j++) acc[i][j] = (f32x4){0.f,0.f,0.f,0.f};
  float m_run[2] = {-1e30f, -1e30f};
  float l_run[2] = {0.f, 0.f};

  const short* kvb = kv  + (long)b*857*3072 + h*96;
  const short* vtb = Vtg + ((long)b*1536 + h*96)*864;

  for (int t=0; t<9; ++t){
    int k0 = t*96;
    for (int c = tid; c < 1152; c += 256){
      int r = c / 12;
      int c12 = c - r*12;
      int key = k0 + r; if (key > 856) key = 856;
      *(bf16x8*)&Kt[r][c12*8] = *(const bf16x8*)&kvb[(long)key*3072 + c12*8];
      *(bf16x8*)&Vs[r][c12*8] = *(const bf16x8*)&vtb[(long)r*864 + k0 + c12*8];
    }
    __syncthreads();

    f32x4 st[6][2];
#pragma unroll
    for (int m=0;m<6;m++){ st[m][0]=(f32x4){0,0,0,0}; st[m][1]=(f32x4){0,0,0,0}; }
#pragma unroll
    for (int kf=0;kf<3;kf++){
      bf16x8 af[6];
#pragma unroll
      for (int m=0;m<6;m++) af[m] = *(const bf16x8*)&Kt[m*16 + l15][kf*32 + g4*8];
#pragma unroll
      for (int m=0;m<6;m++){
        st[m][0] = __builtin_amdgcn_mfma_f32_16x16x32_bf16(af[m], qf[0][kf], st[m][0], 0,0,0);
        st[m][1] = __builtin_amdgcn_mfma_f32_16x16x32_bf16(af[m], qf[1][kf], st[m][1], 0,0,0);
      }
    }

    if (k0 + 96 > 857){
#pragma unroll
      for (int m=0;m<6;m++)
#pragma unroll
        for (int j=0;j<4;j++){
          if (k0 + m*16 + g4*4 + j > 856){ st[m][0][j] = -1e30f; st[m][1][j] = -1e30f; }
        }
    }

#pragma unroll
    for (int n=0;n<2;n++){
      float mx = -1e30f;
#pragma unroll
      for (int m=0;m<6;m++)
#pragma unroll
        for (int j=0;j<4;j++) mx = fmaxf(mx, st[m][n][j]);
      mx = fmaxf(mx, __shfl_xor(mx, 16));
      mx = fmaxf(mx, __shfl_xor(mx, 32));
      float mn = fmaxf(m_run[n], mx);
      float f  = __expf(m_run[n] - mn);
      m_run[n] = mn;
      float s = 0.f;
#pragma unroll
      for (int m=0;m<6;m++)
#pragma unroll
        for (int j=0;j<4;j++){
          float e = __expf(st[m][n][j] - mn);
          st[m][n][j] = e; s += e;
        }
      s += __shfl_xor(s, 16);
      s += __shfl_xor(s, 32);
      l_run[n] = l_run[n]*f + s;
      if (g4 == 0) FAC[w*32 + n*16 + l15] = f;
    }

#pragma unroll
    for (int m=0;m<6;m++)
#pragma unroll
      for (int n=0;n<2;n++){
        short4 pk;
        pk.x = f2bf(st[m][n][0]); pk.y = f2bf(st[m][n][1]);
        pk.z = f2bf(st[m][n][2]); pk.w = f2bf(st[m][n][3]);
        *(short4*)&Pb[w][n*16 + l15][m*16 + g4*4] = pk;
      }

    {
      float4 fj0 = *(const float4*)&FAC[w*32 +  0 + g4*4];
      float4 fj1 = *(const float4*)&FAC[w*32 + 16 + g4*4];
#pragma unroll
      for (int nn=0;nn<6;nn++){
        acc[0][nn][0] *= fj0.x; acc[0][nn][1] *= fj0.y;
        acc[0][nn][2] *= fj0.z; acc[0][nn][3] *= fj0.w;
        acc[1][nn][0] *= fj1.x; acc[1][nn][1] *= fj1.y;
        acc[1][nn][2] *= fj1.z; acc[1][nn][3] *= fj1.w;
      }
    }

#pragma unroll
    for (int kf=0;kf<3;kf++){
      bf16x8 pa0 = *(const bf16x8*)&Pb[w][ 0 + l15][kf*32 + g4*8];
      bf16x8 pa1 = *(const bf16x8*)&Pb[w][16 + l15][kf*32 + g4*8];
#pragma unroll
      for (int nn=0;nn<6;nn++){
        bf16x8 vb = *(const bf16x8*)&Vs[nn*16 + l15][kf*32 + g4*8];
        acc[0][nn] = __builtin_amdgcn_mfma_f32_16x16x32_bf16(pa0, vb, acc[0][nn], 0,0,0);
        acc[1][nn] = __builtin_amdgcn_mfma_f32_16x16x32_bf16(pa1, vb, acc[1][nn], 0,0,0);
      }
    }
    __syncthreads();
  }

  if (g4 == 0){
    FAC[w*32 +  0 + l15] = 1.0f / l_run[0];
    FAC[w*32 + 16 + l15] = 1.0f / l_run[1];
  }
  float4 li0 = *(const float4*)&FAC[w*32 +  0 + g4*4];
  float4 li1 = *(const float4*)&FAC[w*32 + 16 + g4*4];
  float li[2][4] = {{li0.x,li0.y,li0.z,li0.w},{li1.x,li1.y,li1.z,li1.w}};
#pragma unroll
  for (int mo=0;mo<2;mo++)
#pragma unroll
    for (int nn=0;nn<6;nn++)
#pragma unroll
      for (int j=0;j<4;j++){
        int q = w*32 + mo*16 + g4*4 + j;
        int d = nn*16 + l15;
        attn[((long)(b*128+q))*1536 + h*96 + d] = f2bf(acc[mo][nn][j]*li[mo][j]);
      }
}

// ---------------------------------------------------------------------------
// 128x128 2-phase GEMM (verified r2) for preamble shapes.
// ---------------------------------------------------------------------------
template<int GELU, int BIAS, int RES, int OUTF32>
__global__ __launch_bounds__(256)
void gemm_t(const short* __restrict__ A, const short* __restrict__ B,
            void* __restrict__ C, const float* __restrict__ bias,
            const float* __restrict__ res,
            int K, int lda, int ldb, int ldc,
            int Mvalid, int NBmax, int Nwrite,
            int zdiv, long sA1, long sA2, long sB1, long sB2, long sC1, long sC2,
            float scale)
{
  __shared__ __align__(16) short As[2][128*32];
  __shared__ __align__(16) short Bs[2][128*32];

  int z = blockIdx.z;
  int zq = z / zdiv, zr = z - zq*zdiv;
  const short* Ab = A + zq*sA1 + zr*sA2;
  const short* Bb = B + zq*sB1 + zr*sB2;
  long cOff = zq*sC1 + zr*sC2;
  int m0 = blockIdx.y * 128;
  int n0 = blockIdx.x * 128;
  int tid = threadIdx.x;
  int lane = tid & 63;
  int w = tid >> 6;
  int wm = (w >> 1) * 64, wn = (w & 1) * 64;

  int sr = lane >> 2;
  int sc = (lane & 3) * 8;
  int ar0 = m0 + w*32 + sr;
  int br0 = n0 + w*32 + sr;

  int raA0 = ar0;      if (raA0 > Mvalid-1) raA0 = Mvalid-1;
  int raA1 = ar0 + 16; if (raA1 > Mvalid-1) raA1 = Mvalid-1;
  int rbB0 = br0;      if (rbB0 > NBmax-1) rbB0 = NBmax-1;
  int rbB1 = br0 + 16; if (rbB1 > NBmax-1) rbB1 = NBmax-1;
  const short* gA0 = Ab + (long)raA0*lda + sc;
  const short* gA1 = Ab + (long)raA1*lda + sc;
  const short* gB0 = Bb + (long)rbB0*ldb + sc;
  const short* gB1 = Bb + (long)rbB1*ldb + sc;
  int ldsRow0 = (w*32)*32;
  int ldsRow1 = (w*32 + 16)*32;

  f32x4 acc[4][4];
#pragma unroll
  for (int i=0;i<4;i++)
#pragma unroll
    for (int j=0;j<4;j++) acc[i][j] = (f32x4){0.f,0.f,0.f,0.f};

  auto stage = [&](int buf, int kb){
    __builtin_amdgcn_global_load_lds(
        (const __attribute__((address_space(1))) u32*)(gA0 + kb),
        (__attribute__((address_space(3))) u32*)(&As[buf][ldsRow0]), 16, 0, 0);
    __builtin_amdgcn_global_load_lds(
        (const __attribute__((address_space(1))) u32*)(gA1 + kb),
        (__attribute__((address_space(3))) u32*)(&As[buf][ldsRow1]), 16, 0, 0);
    __builtin_amdgcn_global_load_lds(
        (const __attribute__((address_space(1))) u32*)(gB0 + kb),
        (__attribute__((address_space(3))) u32*)(&Bs[buf][ldsRow0]), 16, 0, 0);
    __builtin_amdgcn_global_load_lds(
        (const __attribute__((address_space(1))) u32*)(gB1 + kb),
        (__attribute__((address_space(3))) u32*)(&Bs[buf][ldsRow1]), 16, 0, 0);
  };

  int nt = K >> 5;
  stage(0, 0);
  __syncthreads();

  int kq = (lane >> 4) * 8;
  int rsel = lane & 15;
  int cur = 0;
  for (int t = 0; t < nt; ++t){
    if (t + 1 < nt) stage(cur ^ 1, (t+1)*32);

    bf16x8 af[4], bfr[4];
#pragma unroll
    for (int m=0;m<4;m++) af[m]  = *(const bf16x8*)&As[cur][(wm + m*16 + rsel)*32 + kq];
#pragma unroll
    for (int n=0;n<4;n++) bfr[n] = *(const bf16x8*)&Bs[cur][(wn + n*16 + rsel)*32 + kq];
#pragma unroll
    for (int m=0;m<4;m++)
#pragma unroll
      for (int n=0;n<4;n++)
        acc[m][n] = __builtin_amdgcn_mfma_f32_16x16x32_bf16(af[m], bfr[n], acc[m][n], 0, 0, 0);

    __syncthreads();
    cur ^= 1;
  }

  int cq = (lane >> 4) * 4;
  int csel = lane & 15;
#pragma unroll
  for (int m=0;m<4;m++){
#pragma unroll
    for (int n=0;n<4;n++){
#pragma unroll
      for (int j=0;j<4;j++){
        int gm = m0 + wm + m*16 + cq + j;
        int gn = n0 + wn + n*16 + csel;
        if (gm < Mvalid && gn < Nwrite){
          float v = acc[m][n][j] * scale;
          if (BIAS) v += bias[gn];
          if (GELU) v = 0.5f*v*(1.0f + erff(v*0.70710678118654752f));
          long off = cOff + (long)gm*ldc + gn;
          if (OUTF32){
            float rv = RES ? res[off] : 0.0f;
            ((float*)C)[off] = v + rv;
          } else {
            ((short*)C)[off] = f2bf(v);
          }
        }
      }
    }
  }
}

// ---------------------------------------------------------------------------
__global__ __launch_bounds__(256)
void convT(const float* __restrict__ in, short* __restrict__ out,
           int K, int N, const float* __restrict__ s)
{
  __shared__ float tile[32][33];
  int kb = blockIdx.y*32, nb = blockIdx.x*32;
  int tx = threadIdx.x & 31, ty = threadIdx.x >> 5;
  for (int i = ty; i < 32; i += 8){
    int k = kb + i, n = nb + tx;
    float v = 0.f;
    if (k < K && n < N){ v = in[(long)k*N + n]; if (s) v *= s[k]; }
    tile[i][tx] = v;
  }
  __syncthreads();
  for (int i = ty; i < 32; i += 8){
    int n = nb + i, k = kb + tx;
    if (n < N && k < K) out[(long)n*K + k] = f2bf(tile[tx][i]);
  }
}

__global__ __launch_bounds__(256)
void convT2(const float* __restrict__ in, short* __restrict__ out1,
            short* __restrict__ out2, int K, int N, const float* __restrict__ s)
{
  __shared__ float tile[32][33];
  __shared__ float sv[32];
  int kb = blockIdx.y*32, nb = blockIdx.x*32;
  int tx = threadIdx.x & 31, ty = threadIdx.x >> 5;
  if (threadIdx.x < 32){
    int k = kb + threadIdx.x;
    sv[threadIdx.x] = (k < K) ? s[k] : 0.f;
  }
  for (int i = ty; i < 32; i += 8){
    int k = kb + i, n = nb + tx;
    float v = 0.f;
    if (k < K && n < N) v = in[(long)k*N + n];
    tile[i][tx] = v;
  }
  __syncthreads();
  for (int i = ty; i < 32; i += 8){
    int n = nb + i, k = kb + tx;
    if (n < N && k < K){
      float v = tile[tx][i];
      out2[(long)n*K + k] = f2bf(v);
      out1[(long)n*K + k] = f2bf(v * sv[tx]);
    }
  }
}

__global__ __launch_bounds__(256)
void biasfold(const float* __restrict__ W, const float* __restrict__ bvec, float* __restrict__ outb)
{
  int n = blockIdx.x*256 + threadIdx.x;
  float s = 0.f;
  for (int k=0;k<1152;k++) s += bvec[k]*W[(long)k*3072 + n];
  outb[n] = s;
}

__global__ __launch_bounds__(256)
void cvt_bf16x4(const float* __restrict__ in, short* __restrict__ o, long n)
{
  long i = ((long)blockIdx.x*256 + threadIdx.x)*4;
  if (i >= n) return;
  float4 v = *(const float4*)(in + i);
  o[i+0]=f2bf(v.x); o[i+1]=f2bf(v.y); o[i+2]=f2bf(v.z); o[i+3]=f2bf(v.w);
}

__global__ __launch_bounds__(256)
void latcopy(const float* __restrict__ latents, float* __restrict__ lat)
{
  int idx = blockIdx.x*256 + threadIdx.x;
  int d = idx % 1152; int j = (idx / 1152) % 64; int b = idx / (1152*64);
  lat[((long)b*128 + j)*1152 + d] = latents[j*1152 + d];
}

__global__ __launch_bounds__(256)
void transV(const short* __restrict__ kv, short* __restrict__ Vt)
{
  int b = blockIdx.z;
  __shared__ short tile[32][33];
  int rb = blockIdx.y*32, cb = blockIdx.x*32;
  int tx = threadIdx.x & 31, ty = threadIdx.x >> 5;
  for (int i=ty; i<32; i+=8){
    int r = rb+i, c = cb+tx;
    short v = 0;
    if (r < 857) v = kv[((long)b*857 + r)*3072 + 1536 + c];
    tile[i][tx] = v;
  }
  __syncthreads();
  for (int i=ty;i<32;i+=8){
    int c = cb+i, r = rb+tx;
    Vt[((long)b*1536 + c)*864 + r] = tile[tx][i];
  }
}

template<int OUTF32>
__global__ __launch_bounds__(256)
void ln_k(const float* __restrict__ in, void* __restrict__ outp,
          const float* __restrict__ w, const float* __restrict__ b,
          int grpSel, int grpStride)
{
  const int D = 1152;
  int r = blockIdx.x;
  long ir = (long)(r / grpSel)*grpStride + (r % grpSel);
  const float* x = in + ir*D;
  int tid = threadIdx.x;
  float s1=0.f, s2=0.f;
  float xv[5];
#pragma unroll
  for (int t=0;t<5;t++){
    int i = tid + t*256;
    xv[t] = (i < D) ? x[i] : 0.f;
    s1 += xv[t]; s2 += xv[t]*xv[t];
  }
#pragma unroll
  for (int o=32;o;o>>=1){ s1 += __shfl_xor(s1,o); s2 += __shfl_xor(s2,o); }
  __shared__ float red[8];
  int wid = tid>>6, lane = tid&63;
  if (lane==0){ red[wid]=s1; red[4+wid]=s2; }
  __syncthreads();
  s1 = red[0]+red[1]+red[2]+red[3];
  s2 = red[4]+red[5]+red[6]+red[7];
  float mu = s1 / D;
  float var = s2 / D - mu*mu;
  float rs = rsqrtf(var + 1e-5f);
#pragma unroll
  for (int t=0;t<5;t++){
    int i = tid + t*256;
    if (i >= D) break;
    float v = (xv[t]-mu)*rs;
    if (w) v = v*w[i] + b[i];
    if (OUTF32) ((float*)outp)[(long)r*D + i] = v;
    else        ((short*)outp)[(long)r*D + i] = f2bf(v);
  }
}

// ---------------------------------------------------------------------------

extern "C" void kernel_launch(void* const* d_in, const int* in_sizes, int n_in,
                              void* d_out, int out_size, void* d_ws, size_t ws_size,
                              hipStream_t stream)
{
  const float* x      = (const float*)d_in[0];
  const float* tein   = (const float*)d_in[1];
  const float* lat0   = (const float*)d_in[2];
  const float* txt_w1 = (const float*)d_in[3];
  const float* txt_b1 = (const float*)d_in[4];
  const float* txt_w2 = (const float*)d_in[5];
  const float* txt_b2 = (const float*)d_in[6];
  const float* nm_w   = (const float*)d_in[7];
  const float* nm_b   = (const float*)d_in[8];
  const float* nl_w   = (const float*)d_in[9];
  const float* nl_b   = (const float*)d_in[10];
  const float* Wq     = (const float*)d_in[11];
  const float* Wkv    = (const float*)d_in[12];
  const float* Wo     = (const float*)d_in[13];
  const float* ffln_w = (const float*)d_in[14];
  const float* ffln_b = (const float*)d_in[15];
  const float* ff_w1  = (const float*)d_in[16];
  const float* ff_w2  = (const float*)d_in[17];
  const float* oln_w  = (const float*)d_in[18];
  const float* oln_b  = (const float*)d_in[19];
  float* out = (float*)d_out;
  (void)in_sizes; (void)n_in; (void)out_size; (void)ws_size;

  char* base = (char*)d_ws;
  size_t off = 0;
  auto alloc = [&](size_t bytes)->char*{
    char* r = base + off;
    off += (bytes + 255) & ~(size_t)255;
    return r;
  };
  short* wT    = (short*)alloc(4608ULL*1152*2);
  short* wTx   = (short*)alloc(3072ULL*1152*2);
  float* biasf = (float*)alloc(3072*4);
  short* xnorm = (short*)alloc(23328ULL*1152*2);
  float* lat   = (float*)alloc(4096ULL*1152*4);
  short* lm    = (short*)alloc(4096ULL*1152*2);
  short* qb    = (short*)alloc(4096ULL*1536*2);
  short* kv    = (short*)alloc(27424ULL*3072*2);
  short* Vt    = (short*)alloc(32ULL*1536*864*2);
  short* SP    = (short*)alloc(2048ULL*4096*2 + 2048ULL*1152*2);
  short* attn  = (short*)alloc(4096ULL*1536*2);
  short* ffh   = (short*)alloc(4096ULL*4608*2);
  short* txtin = SP;
  short* txth  = SP + 2048ULL*4096;

  // ---- preamble ----
  cvt_bf16x4<<<8192,256,0,stream>>>(tein, txtin, 2048LL*4096);
  convT<<<dim3(36,128),256,0,stream>>>(txt_w1, wT, 4096, 1152, nullptr);
  gemm_t<1,1,0,0><<<dim3(9,16,1),256,0,stream>>>(txtin, wT, txth, txt_b1, nullptr,
      4096,4096,4096,1152, 2048,1152,1152, 1, 0,0,0,0,0,0, 1.f);
  convT<<<dim3(36,36),256,0,stream>>>(txt_w2, wT, 1152, 1152, nullptr);
  gemm_t<0,1,0,1><<<dim3(9,1,32),256,0,stream>>>(txth, wT, lat + 64*1152, txt_b2, nullptr,
      1152,1152,1152,1152, 64,1152,1152, 1, 64L*1152,0, 0,0, 128L*1152,0, 1.f);
  latcopy<<<9216,256,0,stream>>>(lat0, lat);

  ln_k<0><<<23328,256,0,stream>>>(x, xnorm, nullptr, nullptr, 1<<28, 0);

  for (int L=0; L<6; L++){
    const float* WqL  = Wq    + (size_t)L*1152*1536;
    const float* WkvL = Wkv   + (size_t)L*1152*3072;
    const float* WoL  = Wo    + (size_t)L*1536*1152;
    const float* fw1  = ff_w1 + (size_t)L*1152*4608;
    const float* fw2  = ff_w2 + (size_t)L*4608*1152;

    // lm = LN(lat; nl)
    ln_k<0><<<4096,256,0,stream>>>(lat, lm, nl_w + L*1152, nl_b + L*1152, 1<<28, 0);

    // weight transposes
    convT<<<dim3(48,36),256,0,stream>>>(WqL, wT, 1152, 1536, nullptr);
    convT2<<<dim3(96,36),256,0,stream>>>(WkvL, wTx, wT + 1536*1152, 1152, 3072, nm_w + L*1152);

    // fused q | kv-latent (M=4096, N=4608)
    gemm_v2<0,0,0,0,2><<<dim3(18,32),512,0,stream>>>(lm, wT, qb, kv, nullptr, nullptr,
        1152,1152,1152,0, 4096, 4608, 4608);

    // kv x part (M=23328 -> 184 M-blocks for %8 swizzle; clamp handles pad)
    biasfold<<<12,256,0,stream>>>(WkvL, nm_b + L*1152, biasf);
    gemm_v2<0,1,0,0,1><<<dim3(12,184),512,0,stream>>>(xnorm, wTx, kv, nullptr, biasf, nullptr,
        1152,1152,1152,0, 23328, 3072, 3072);

    // Vt = V^T per batch (zero-padded to 864 keys)
    transV<<<dim3(48,27,32),256,0,stream>>>(kv, Vt);

    // fused flash attention
    flash_attn<<<512,256,0,stream>>>(qb, kv, Vt, attn);

    // lat += attn @ Wo
    convT<<<dim3(36,48),256,0,stream>>>(WoL, wT, 1536, 1152, nullptr);
    gemm_v2<0,0,1,1,0><<<dim3(5,32),512,0,stream>>>(attn, wT, lat, nullptr, nullptr, lat,
        1536,1536,1536,1152, 4096, 1152, 1152);

    // FF
    ln_k<0><<<4096,256,0,stream>>>(lat, lm, ffln_w + L*1152, ffln_b + L*1152, 1<<28, 0);
    convT<<<dim3(144,36),256,0,stream>>>(fw1, wT, 1152, 4608, nullptr);
    gemm_v2<1,0,0,0,0><<<dim3(18,32),512,0,stream>>>(lm, wT, ffh, nullptr, nullptr, nullptr,
        1152,1152,1152,4608, 4096, 4608, 4608);
    convT<<<dim3(36,144),256,0,stream>>>(fw2, wT, 4608, 1152, nullptr);
    gemm_v2<0,0,1,1,0><<<dim3(5,32),512,0,stream>>>(ffh, wT, lat, nullptr, nullptr, lat,
        4608,4608,4608,1152, 4096, 1152, 1152);
  }

  ln_k<1><<<2048,256,0,stream>>>(lat, out, oln_w, oln_b, 64, 128);
}

// Round 10
// 4563.713 us; speedup vs baseline: 1.2906x; 1.0554x over previous
//
#include <hip/hip_runtime.h>
#include <hip/hip_bf16.h>
#include <math.h>

// InstructPerceiverResampler on MI355X (gfx950).
// Round 10: (1) gemm_v2 triple-buffer LDS (72KB) + counted vmcnt(3), prefetch
// distance 2 -> load latency fully hidden under 2 K-steps of MFMA; (2) ff2/Wo
// split-K x2 via blockIdx.z (grid 320 vs 160) with fp32 partials + reduce2
// (lat += p0 + p1). flash_attn / gemm_t / helpers unchanged (R8/R9 verified).

typedef __attribute__((ext_vector_type(4))) float f32x4;
typedef __attribute__((ext_vector_type(8))) short bf16x8;
typedef unsigned int u32;

#define DEV __device__ __forceinline__

DEV float bf2f(short s){ union{u32 u; float f;} v; v.u = ((u32)(unsigned short)s) << 16; return v.f; }
DEV short f2bf(float f){
  union{float f; u32 u;} v; v.f = f;
  u32 r = (v.u + 0x7FFFu + ((v.u >> 16) & 1u)) >> 16;
  return (short)r;
}

DEV u32 lds_off(const short* p){
  return (u32)(uintptr_t)(__attribute__((address_space(3))) const short*)p;
}
template<int OFF>
DEV bf16x8 dsro(u32 addr){
  bf16x8 r;
  asm volatile("ds_read_b128 %0, %1 offset:%2" : "=v"(r) : "v"(addr), "i"(OFF));
  return r;
}

// ---------------------------------------------------------------------------
// gemm_v2: C[m,n] = A[m,k]*B[n,k] (+bias)(+gelu)(+res), tiles 128x256, BK=32.
// 512 thr / 8 waves (2 x 4 of 64x64). Triple-buffered LDS 3 x (A 8KB|B 16KB)
// = 72 KiB -> 2 blocks/CU. Counted vmcnt(3), prefetch distance 2.
// KSPLIT: blockIdx.z selects K-chunk (K = per-chunk size); partial fp32 out
// at Cv + z*Mvalid*ldc (OUTF32=1, RES=0, CMAP=0 required).
// ---------------------------------------------------------------------------
template<int GELU, int BIAS, int RES, int OUTF32, int CMAP, int KSPLIT>
__global__ __launch_bounds__(512, 4)
void gemm_v2(const short* __restrict__ A, const short* __restrict__ Bm,
             void* __restrict__ Cv, short* __restrict__ C2,
             const float* __restrict__ bias, const float* __restrict__ res,
             int K, int lda, int ldb, int ldc,
             int Mvalid, int NBmax, int Nwrite)
{
  __shared__ __align__(16) short LDS[36864];   // 72 KiB: 3 bufs x (A 8KB | B 16KB)

  int nwg = gridDim.x * gridDim.y;
  int bid = blockIdx.y * gridDim.x + blockIdx.x;
  if ((nwg & 7) == 0){ int chunk = nwg >> 3; bid = (bid & 7)*chunk + (bid >> 3); }
  int by = bid / gridDim.x;
  int m0 = by * 128;
  int n0 = (bid - by*gridDim.x) * 256;
  int kzoff = KSPLIT ? (int)blockIdx.z * K : 0;

  int tid = threadIdx.x, lane = tid & 63, w = tid >> 6;
  int wr = w >> 2, wc = w & 3;          // wave -> (2 x 4) of 64x64 outputs
  int rsel = lane & 15, g4 = lane >> 4;

  // ---- staging source pointers (loop-invariant) ----
  int sl = lane >> 3;
  int l  = (lane & 7) ^ sl;             // logical block 0..7
  int lc = (l & 3) * 8;                 // source col (shorts)
  int lh = l >> 2;                      // source half
  const short* gA;
  { int r = m0 + w*8 + sl + lh*64; if (r > Mvalid-1) r = Mvalid-1;
    gA = A + (long)r*lda + lc + kzoff; }
  const short* gB0;
  { int r = n0 + w*8 + sl + lh*128; if (r > NBmax-1) r = NBmax-1;
    gB0 = Bm + (long)r*ldb + lc + kzoff; }
  const short* gB1;
  { int r = n0 + 64 + w*8 + sl + lh*128; if (r > NBmax-1) r = NBmax-1;
    gB1 = Bm + (long)r*ldb + lc + kzoff; }
  char* dA  = (char*)LDS + w*1024;
  char* dB0 = (char*)LDS + 8192  + w*1024;
  char* dB1 = (char*)LDS + 16384 + w*1024;

#define GLDS(src, dst) __builtin_amdgcn_global_load_lds( \
      (const __attribute__((address_space(1))) u32*)(src), \
      (__attribute__((address_space(3))) u32*)(dst), 16, 0, 0)
#define STAGE(bo, tau) do { \
    int kb = (tau)*32; \
    GLDS(gA  + kb, dA  + (bo)); \
    GLDS(gB0 + kb, dB0 + (bo)); \
    GLDS(gB1 + kb, dB1 + (bo)); \
  } while(0)

  // ---- reader base addrs (bytes); frag offsets are instruction immediates ----
  u32 base = lds_off(LDS);
  u32 aAddr = base + (u32)(rsel*128 + (((wr*4 + g4) ^ (rsel & 7))*16));
  u32 bAddr = base + 8192u
            + (u32)(((wc & 1)*64 + rsel)*128 + ((((wc >> 1)*4 + g4) ^ (rsel & 7))*16));

  int nt = K >> 5;

  f32x4 acc[4][4];
#pragma unroll
  for (int i=0;i<4;i++)
#pragma unroll
    for (int j=0;j<4;j++) acc[i][j] = (f32x4){0.f,0.f,0.f,0.f};

  // prologue: tiles 0 and 1 in flight (prefetch distance 2)
  STAGE(0u, 0);
  if (nt > 1) STAGE(24576u, 1);

  u32 boCur = 0;
#pragma unroll 1
  for (int t=0; t<nt; ++t){
    if (t == nt-1) { asm volatile("s_waitcnt vmcnt(0)" ::: "memory"); }
    else           { asm volatile("s_waitcnt vmcnt(3)" ::: "memory"); }
    asm volatile("s_barrier" ::: "memory");
    u32 aa = aAddr + boCur, bb = bAddr + boCur;
    bf16x8 af[4], bfr[4];
    af[0]  = dsro<0>(aa);    af[1]  = dsro<2048>(aa);
    af[2]  = dsro<4096>(aa); af[3]  = dsro<6144>(aa);
    bfr[0] = dsro<0>(bb);    bfr[1] = dsro<2048>(bb);
    bfr[2] = dsro<4096>(bb); bfr[3] = dsro<6144>(bb);
    if (t+2 < nt){
      u32 boN2 = boCur + 49152u; if (boN2 >= 73728u) boN2 -= 73728u;
      STAGE(boN2, t+2);
    }
    asm volatile("s_waitcnt lgkmcnt(0)" ::: "memory");
    __builtin_amdgcn_sched_barrier(0);
    __builtin_amdgcn_s_setprio(1);
#pragma unroll
    for (int mi=0; mi<4; mi++)
#pragma unroll
      for (int nn=0; nn<4; nn++)
        acc[mi][nn] = __builtin_amdgcn_mfma_f32_16x16x32_bf16(af[mi], bfr[nn], acc[mi][nn], 0, 0, 0);
    __builtin_amdgcn_s_setprio(0);
    boCur += 24576u; if (boCur == 73728u) boCur = 0;
  }
#undef STAGE
#undef GLDS

  // ---- epilogue: C/D frag layout col=lane&15, row=(lane>>4)*4+j ----
  int cq = g4 * 4;
  int csel = rsel;
#pragma unroll
  for (int mi=0; mi<4; mi++){
#pragma unroll
    for (int nn=0; nn<4; nn++){
#pragma unroll
      for (int j=0; j<4; j++){
        int gm = m0 + wr*64 + mi*16 + cq + j;
        int gn = n0 + wc*64 + nn*16 + csel;
        if (gm < Mvalid && gn < Nwrite){
          float v = acc[mi][nn][j];
          if (BIAS) v += bias[gn];
          if (GELU) v = 0.5f*v*(1.0f + erff(v*0.70710678118654752f));
          if (CMAP == 0){
            long off = (long)gm*ldc + gn;
            if (KSPLIT) off += (long)blockIdx.z * ((long)Mvalid * ldc);
            if (OUTF32){
              float rv = RES ? res[off] : 0.0f;
              ((float*)Cv)[off] = v + rv;
            } else {
              ((short*)Cv)[off] = f2bf(v);
            }
          } else if (CMAP == 1){
            int bb2 = gm / 729;
            int jj = gm - bb2*729;
            ((short*)Cv)[((long)bb2*857 + jj)*3072 + gn] = f2bf(v);
          } else {
            if (gn < 1536){
              ((short*)Cv)[(long)gm*1536 + gn] = f2bf(v * 0.1020620726159657f);
            } else {
              int bb2 = gm >> 7, jj = gm & 127;
              C2[((long)bb2*857 + 729 + jj)*3072 + (gn - 1536)] = f2bf(v);
            }
          }
        }
      }
    }
  }
}

// lat[i] += p[i] + p[i+n]   (split-K reduction + residual, float4)
__global__ __launch_bounds__(256)
void reduce2(float* __restrict__ lat, const float* __restrict__ p, long n)
{
  long i = ((long)blockIdx.x*256 + threadIdx.x)*4;
  long stride = (long)gridDim.x*256*4;
  for (; i < n; i += stride){
    float4 a = *(const float4*)(lat + i);
    float4 b = *(const float4*)(p + i);
    float4 c = *(const float4*)(p + n + i);
    a.x += b.x + c.x; a.y += b.y + c.y; a.z += b.z + c.z; a.w += b.w + c.w;
    *(float4*)(lat + i) = a;
  }
}

// ---------------------------------------------------------------------------
// Flash attention (R8, verified): one block per (b,h). 4 waves x 32 q-rows.
// ---------------------------------------------------------------------------
__global__ __launch_bounds__(256)
void flash_attn(const short* __restrict__ qb, const short* __restrict__ kv,
                const short* __restrict__ Vtg, short* __restrict__ attn)
{
  __shared__ short Kt[96][104];
  __shared__ short Vs[96][104];
  __shared__ short Pb[4][32][104];
  __shared__ float FAC[128];

  int z = blockIdx.x;
  int b = z >> 4, h = z & 15;
  int tid = threadIdx.x;
  int lane = tid & 63;
  int w = tid >> 6;
  int l15 = lane & 15, g4 = lane >> 4;

  bf16x8 qf[2][3];
#pragma unroll
  for (int n=0;n<2;n++)
#pragma unroll
    for (int kf=0;kf<3;kf++)
      qf[n][kf] = *(const bf16x8*)&qb[((long)(b*128 + w*32 + n*16 + l15))*1536
                                     + h*96 + kf*32 + g4*8];

  f32x4 acc[2][6];
#pragma unroll
  for (int i=0;i<2;i++)
#pragma unroll
    for (int j=0;j<6;j++) acc[i][j] = (f32x4){0.f,0.f,0.f,0.f};
  float m_run[2] = {-1e30f, -1e30f};
  float l_run[2] = {0.f, 0.f};

  const short* kvb = kv  + (long)b*857*3072 + h*96;
  const short* vtb = Vtg + ((long)b*1536 + h*96)*864;

  for (int t=0; t<9; ++t){
    int k0 = t*96;
    for (int c = tid; c < 1152; c += 256){
      int r = c / 12;
      int c12 = c - r*12;
      int key = k0 + r; if (key > 856) key = 856;
      *(bf16x8*)&Kt[r][c12*8] = *(const bf16x8*)&kvb[(long)key*3072 + c12*8];
      *(bf16x8*)&Vs[r][c12*8] = *(const bf16x8*)&vtb[(long)r*864 + k0 + c12*8];
    }
    __syncthreads();

    f32x4 st[6][2];
#pragma unroll
    for (int m=0;m<6;m++){ st[m][0]=(f32x4){0,0,0,0}; st[m][1]=(f32x4){0,0,0,0}; }
#pragma unroll
    for (int kf=0;kf<3;kf++){
      bf16x8 af[6];
#pragma unroll
      for (int m=0;m<6;m++) af[m] = *(const bf16x8*)&Kt[m*16 + l15][kf*32 + g4*8];
#pragma unroll
      for (int m=0;m<6;m++){
        st[m][0] = __builtin_amdgcn_mfma_f32_16x16x32_bf16(af[m], qf[0][kf], st[m][0], 0,0,0);
        st[m][1] = __builtin_amdgcn_mfma_f32_16x16x32_bf16(af[m], qf[1][kf], st[m][1], 0,0,0);
      }
    }

    if (k0 + 96 > 857){
#pragma unroll
      for (int m=0;m<6;m++)
#pragma unroll
        for (int j=0;j<4;j++){
          if (k0 + m*16 + g4*4 + j > 856){ st[m][0][j] = -1e30f; st[m][1][j] = -1e30f; }
        }
    }

#pragma unroll
    for (int n=0;n<2;n++){
      float mx = -1e30f;
#pragma unroll
      for (int m=0;m<6;m++)
#pragma unroll
        for (int j=0;j<4;j++) mx = fmaxf(mx, st[m][n][j]);
      mx = fmaxf(mx, __shfl_xor(mx, 16));
      mx = fmaxf(mx, __shfl_xor(mx, 32));
      float mn = fmaxf(m_run[n], mx);
      float f  = __expf(m_run[n] - mn);
      m_run[n] = mn;
      float s = 0.f;
#pragma unroll
      for (int m=0;m<6;m++)
#pragma unroll
        for (int j=0;j<4;j++){
          float e = __expf(st[m][n][j] - mn);
          st[m][n][j] = e; s += e;
        }
      s += __shfl_xor(s, 16);
      s += __shfl_xor(s, 32);
      l_run[n] = l_run[n]*f + s;
      if (g4 == 0) FAC[w*32 + n*16 + l15] = f;
    }

#pragma unroll
    for (int m=0;m<6;m++)
#pragma unroll
      for (int n=0;n<2;n++){
        short4 pk;
        pk.x = f2bf(st[m][n][0]); pk.y = f2bf(st[m][n][1]);
        pk.z = f2bf(st[m][n][2]); pk.w = f2bf(st[m][n][3]);
        *(short4*)&Pb[w][n*16 + l15][m*16 + g4*4] = pk;
      }

    {
      float4 fj0 = *(const float4*)&FAC[w*32 +  0 + g4*4];
      float4 fj1 = *(const float4*)&FAC[w*32 + 16 + g4*4];
#pragma unroll
      for (int nn=0;nn<6;nn++){
        acc[0][nn][0] *= fj0.x; acc[0][nn][1] *= fj0.y;
        acc[0][nn][2] *= fj0.z; acc[0][nn][3] *= fj0.w;
        acc[1][nn][0] *= fj1.x; acc[1][nn][1] *= fj1.y;
        acc[1][nn][2] *= fj1.z; acc[1][nn][3] *= fj1.w;
      }
    }

#pragma unroll
    for (int kf=0;kf<3;kf++){
      bf16x8 pa0 = *(const bf16x8*)&Pb[w][ 0 + l15][kf*32 + g4*8];
      bf16x8 pa1 = *(const bf16x8*)&Pb[w][16 + l15][kf*32 + g4*8];
#pragma unroll
      for (int nn=0;nn<6;nn++){
        bf16x8 vb = *(const bf16x8*)&Vs[nn*16 + l15][kf*32 + g4*8];
        acc[0][nn] = __builtin_amdgcn_mfma_f32_16x16x32_bf16(pa0, vb, acc[0][nn], 0,0,0);
        acc[1][nn] = __builtin_amdgcn_mfma_f32_16x16x32_bf16(pa1, vb, acc[1][nn], 0,0,0);
      }
    }
    __syncthreads();
  }

  if (g4 == 0){
    FAC[w*32 +  0 + l15] = 1.0f / l_run[0];
    FAC[w*32 + 16 + l15] = 1.0f / l_run[1];
  }
  float4 li0 = *(const float4*)&FAC[w*32 +  0 + g4*4];
  float4 li1 = *(const float4*)&FAC[w*32 + 16 + g4*4];
  float li[2][4] = {{li0.x,li0.y,li0.z,li0.w},{li1.x,li1.y,li1.z,li1.w}};
#pragma unroll
  for (int mo=0;mo<2;mo++)
#pragma unroll
    for (int nn=0;nn<6;nn++)
#pragma unroll
      for (int j=0;j<4;j++){
        int q = w*32 + mo*16 + g4*4 + j;
        int d = nn*16 + l15;
        attn[((long)(b*128+q))*1536 + h*96 + d] = f2bf(acc[mo][nn][j]*li[mo][j]);
      }
}

// ---------------------------------------------------------------------------
// 128x128 2-phase GEMM (verified r2) for preamble shapes.
// ---------------------------------------------------------------------------
template<int GELU, int BIAS, int RES, int OUTF32>
__global__ __launch_bounds__(256)
void gemm_t(const short* __restrict__ A, const short* __restrict__ B,
            void* __restrict__ C, const float* __restrict__ bias,
            const float* __restrict__ res,
            int K, int lda, int ldb, int ldc,
            int Mvalid, int NBmax, int Nwrite,
            int zdiv, long sA1, long sA2, long sB1, long sB2, long sC1, long sC2,
            float scale)
{
  __shared__ __align__(16) short As[2][128*32];
  __shared__ __align__(16) short Bs[2][128*32];

  int z = blockIdx.z;
  int zq = z / zdiv, zr = z - zq*zdiv;
  const short* Ab = A + zq*sA1 + zr*sA2;
  const short* Bb = B + zq*sB1 + zr*sB2;
  long cOff = zq*sC1 + zr*sC2;
  int m0 = blockIdx.y * 128;
  int n0 = blockIdx.x * 128;
  int tid = threadIdx.x;
  int lane = tid & 63;
  int w = tid >> 6;
  int wm = (w >> 1) * 64, wn = (w & 1) * 64;

  int sr = lane >> 2;
  int sc = (lane & 3) * 8;
  int ar0 = m0 + w*32 + sr;
  int br0 = n0 + w*32 + sr;

  int raA0 = ar0;      if (raA0 > Mvalid-1) raA0 = Mvalid-1;
  int raA1 = ar0 + 16; if (raA1 > Mvalid-1) raA1 = Mvalid-1;
  int rbB0 = br0;      if (rbB0 > NBmax-1) rbB0 = NBmax-1;
  int rbB1 = br0 + 16; if (rbB1 > NBmax-1) rbB1 = NBmax-1;
  const short* gA0 = Ab + (long)raA0*lda + sc;
  const short* gA1 = Ab + (long)raA1*lda + sc;
  const short* gB0 = Bb + (long)rbB0*ldb + sc;
  const short* gB1 = Bb + (long)rbB1*ldb + sc;
  int ldsRow0 = (w*32)*32;
  int ldsRow1 = (w*32 + 16)*32;

  f32x4 acc[4][4];
#pragma unroll
  for (int i=0;i<4;i++)
#pragma unroll
    for (int j=0;j<4;j++) acc[i][j] = (f32x4){0.f,0.f,0.f,0.f};

  auto stage = [&](int buf, int kb){
    __builtin_amdgcn_global_load_lds(
        (const __attribute__((address_space(1))) u32*)(gA0 + kb),
        (__attribute__((address_space(3))) u32*)(&As[buf][ldsRow0]), 16, 0, 0);
    __builtin_amdgcn_global_load_lds(
        (const __attribute__((address_space(1))) u32*)(gA1 + kb),
        (__attribute__((address_space(3))) u32*)(&As[buf][ldsRow1]), 16, 0, 0);
    __builtin_amdgcn_global_load_lds(
        (const __attribute__((address_space(1))) u32*)(gB0 + kb),
        (__attribute__((address_space(3))) u32*)(&Bs[buf][ldsRow0]), 16, 0, 0);
    __builtin_amdgcn_global_load_lds(
        (const __attribute__((address_space(1))) u32*)(gB1 + kb),
        (__attribute__((address_space(3))) u32*)(&Bs[buf][ldsRow1]), 16, 0, 0);
  };

  int nt = K >> 5;
  stage(0, 0);
  __syncthreads();

  int kq = (lane >> 4) * 8;
  int rsel = lane & 15;
  int cur = 0;
  for (int t = 0; t < nt; ++t){
    if (t + 1 < nt) stage(cur ^ 1, (t+1)*32);

    bf16x8 af[4], bfr[4];
#pragma unroll
    for (int m=0;m<4;m++) af[m]  = *(const bf16x8*)&As[cur][(wm + m*16 + rsel)*32 + kq];
#pragma unroll
    for (int n=0;n<4;n++) bfr[n] = *(const bf16x8*)&Bs[cur][(wn + n*16 + rsel)*32 + kq];
#pragma unroll
    for (int m=0;m<4;m++)
#pragma unroll
      for (int n=0;n<4;n++)
        acc[m][n] = __builtin_amdgcn_mfma_f32_16x16x32_bf16(af[m], bfr[n], acc[m][n], 0, 0, 0);

    __syncthreads();
    cur ^= 1;
  }

  int cq = (lane >> 4) * 4;
  int csel = lane & 15;
#pragma unroll
  for (int m=0;m<4;m++){
#pragma unroll
    for (int n=0;n<4;n++){
#pragma unroll
      for (int j=0;j<4;j++){
        int gm = m0 + wm + m*16 + cq + j;
        int gn = n0 + wn + n*16 + csel;
        if (gm < Mvalid && gn < Nwrite){
          float v = acc[m][n][j] * scale;
          if (BIAS) v += bias[gn];
          if (GELU) v = 0.5f*v*(1.0f + erff(v*0.70710678118654752f));
          long off = cOff + (long)gm*ldc + gn;
          if (OUTF32){
            float rv = RES ? res[off] : 0.0f;
            ((float*)C)[off] = v + rv;
          } else {
            ((short*)C)[off] = f2bf(v);
          }
        }
      }
    }
  }
}

// ---------------------------------------------------------------------------
__global__ __launch_bounds__(256)
void convT(const float* __restrict__ in, short* __restrict__ out,
           int K, int N, const float* __restrict__ s)
{
  __shared__ float tile[32][33];
  int kb = blockIdx.y*32, nb = blockIdx.x*32;
  int tx = threadIdx.x & 31, ty = threadIdx.x >> 5;
  for (int i = ty; i < 32; i += 8){
    int k = kb + i, n = nb + tx;
    float v = 0.f;
    if (k < K && n < N){ v = in[(long)k*N + n]; if (s) v *= s[k]; }
    tile[i][tx] = v;
  }
  __syncthreads();
  for (int i = ty; i < 32; i += 8){
    int n = nb + i, k = kb + tx;
    if (n < N && k < K) out[(long)n*K + k] = f2bf(tile[tx][i]);
  }
}

__global__ __launch_bounds__(256)
void convT2(const float* __restrict__ in, short* __restrict__ out1,
            short* __restrict__ out2, int K, int N, const float* __restrict__ s)
{
  __shared__ float tile[32][33];
  __shared__ float sv[32];
  int kb = blockIdx.y*32, nb = blockIdx.x*32;
  int tx = threadIdx.x & 31, ty = threadIdx.x >> 5;
  if (threadIdx.x < 32){
    int k = kb + threadIdx.x;
    sv[threadIdx.x] = (k < K) ? s[k] : 0.f;
  }
  for (int i = ty; i < 32; i += 8){
    int k = kb + i, n = nb + tx;
    float v = 0.f;
    if (k < K && n < N) v = in[(long)k*N + n];
    tile[i][tx] = v;
  }
  __syncthreads();
  for (int i = ty; i < 32; i += 8){
    int n = nb + i, k = kb + tx;
    if (n < N && k < K){
      float v = tile[tx][i];
      out2[(long)n*K + k] = f2bf(v);
      out1[(long)n*K + k] = f2bf(v * sv[tx]);
    }
  }
}

__global__ __launch_bounds__(256)
void biasfold(const float* __restrict__ W, const float* __restrict__ bvec, float* __restrict__ outb)
{
  int n = blockIdx.x*256 + threadIdx.x;
  float s = 0.f;
  for (int k=0;k<1152;k++) s += bvec[k]*W[(long)k*3072 + n];
  outb[n] = s;
}

__global__ __launch_bounds__(256)
void cvt_bf16x4(const float* __restrict__ in, short* __restrict__ o, long n)
{
  long i = ((long)blockIdx.x*256 + threadIdx.x)*4;
  if (i >= n) return;
  float4 v = *(const float4*)(in + i);
  o[i+0]=f2bf(v.x); o[i+1]=f2bf(v.y); o[i+2]=f2bf(v.z); o[i+3]=f2bf(v.w);
}

__global__ __launch_bounds__(256)
void latcopy(const float* __restrict__ latents, float* __restrict__ lat)
{
  int idx = blockIdx.x*256 + threadIdx.x;
  int d = idx % 1152; int j = (idx / 1152) % 64; int b = idx / (1152*64);
  lat[((long)b*128 + j)*1152 + d] = latents[j*1152 + d];
}

__global__ __launch_bounds__(256)
void transV(const short* __restrict__ kv, short* __restrict__ Vt)
{
  int b = blockIdx.z;
  __shared__ short tile[32][33];
  int rb = blockIdx.y*32, cb = blockIdx.x*32;
  int tx = threadIdx.x & 31, ty = threadIdx.x >> 5;
  for (int i=ty; i<32; i+=8){
    int r = rb+i, c = cb+tx;
    short v = 0;
    if (r < 857) v = kv[((long)b*857 + r)*3072 + 1536 + c];
    tile[i][tx] = v;
  }
  __syncthreads();
  for (int i=ty;i<32;i+=8){
    int c = cb+i, r = rb+tx;
    Vt[((long)b*1536 + c)*864 + r] = tile[tx][i];
  }
}

template<int OUTF32>
__global__ __launch_bounds__(256)
void ln_k(const float* __restrict__ in, void* __restrict__ outp,
          const float* __restrict__ w, const float* __restrict__ b,
          int grpSel, int grpStride)
{
  const int D = 1152;
  int r = blockIdx.x;
  long ir = (long)(r / grpSel)*grpStride + (r % grpSel);
  const float* x = in + ir*D;
  int tid = threadIdx.x;
  float s1=0.f, s2=0.f;
  float xv[5];
#pragma unroll
  for (int t=0;t<5;t++){
    int i = tid + t*256;
    xv[t] = (i < D) ? x[i] : 0.f;
    s1 += xv[t]; s2 += xv[t]*xv[t];
  }
#pragma unroll
  for (int o=32;o;o>>=1){ s1 += __shfl_xor(s1,o); s2 += __shfl_xor(s2,o); }
  __shared__ float red[8];
  int wid = tid>>6, lane = tid&63;
  if (lane==0){ red[wid]=s1; red[4+wid]=s2; }
  __syncthreads();
  s1 = red[0]+red[1]+red[2]+red[3];
  s2 = red[4]+red[5]+red[6]+red[7];
  float mu = s1 / D;
  float var = s2 / D - mu*mu;
  float rs = rsqrtf(var + 1e-5f);
#pragma unroll
  for (int t=0;t<5;t++){
    int i = tid + t*256;
    if (i >= D) break;
    float v = (xv[t]-mu)*rs;
    if (w) v = v*w[i] + b[i];
    if (OUTF32) ((float*)outp)[(long)r*D + i] = v;
    else        ((short*)outp)[(long)r*D + i] = f2bf(v);
  }
}

// ---------------------------------------------------------------------------

extern "C" void kernel_launch(void* const* d_in, const int* in_sizes, int n_in,
                              void* d_out, int out_size, void* d_ws, size_t ws_size,
                              hipStream_t stream)
{
  const float* x      = (const float*)d_in[0];
  const float* tein   = (const float*)d_in[1];
  const float* lat0   = (const float*)d_in[2];
  const float* txt_w1 = (const float*)d_in[3];
  const float* txt_b1 = (const float*)d_in[4];
  const float* txt_w2 = (const float*)d_in[5];
  const float* txt_b2 = (const float*)d_in[6];
  const float* nm_w   = (const float*)d_in[7];
  const float* nm_b   = (const float*)d_in[8];
  const float* nl_w   = (const float*)d_in[9];
  const float* nl_b   = (const float*)d_in[10];
  const float* Wq     = (const float*)d_in[11];
  const float* Wkv    = (const float*)d_in[12];
  const float* Wo     = (const float*)d_in[13];
  const float* ffln_w = (const float*)d_in[14];
  const float* ffln_b = (const float*)d_in[15];
  const float* ff_w1  = (const float*)d_in[16];
  const float* ff_w2  = (const float*)d_in[17];
  const float* oln_w  = (const float*)d_in[18];
  const float* oln_b  = (const float*)d_in[19];
  float* out = (float*)d_out;
  (void)in_sizes; (void)n_in; (void)out_size; (void)ws_size;

  char* base = (char*)d_ws;
  size_t off = 0;
  auto alloc = [&](size_t bytes)->char*{
    char* r = base + off;
    off += (bytes + 255) & ~(size_t)255;
    return r;
  };
  short* wT    = (short*)alloc(4608ULL*1152*2);
  short* wTx   = (short*)alloc(3072ULL*1152*2);
  float* biasf = (float*)alloc(3072*4);
  float* ppart = (float*)alloc(2ULL*4096*1152*4);   // split-K partials
  short* xnorm = (short*)alloc(23328ULL*1152*2);
  float* lat   = (float*)alloc(4096ULL*1152*4);
  short* lm    = (short*)alloc(4096ULL*1152*2);
  short* qb    = (short*)alloc(4096ULL*1536*2);
  short* kv    = (short*)alloc(27424ULL*3072*2);
  short* Vt    = (short*)alloc(32ULL*1536*864*2);
  short* SP    = (short*)alloc(2048ULL*4096*2 + 2048ULL*1152*2);
  short* attn  = (short*)alloc(4096ULL*1536*2);
  short* ffh   = (short*)alloc(4096ULL*4608*2);
  short* txtin = SP;
  short* txth  = SP + 2048ULL*4096;

  // ---- preamble ----
  cvt_bf16x4<<<8192,256,0,stream>>>(tein, txtin, 2048LL*4096);
  convT<<<dim3(36,128),256,0,stream>>>(txt_w1, wT, 4096, 1152, nullptr);
  gemm_t<1,1,0,0><<<dim3(9,16,1),256,0,stream>>>(txtin, wT, txth, txt_b1, nullptr,
      4096,4096,4096,1152, 2048,1152,1152, 1, 0,0,0,0,0,0, 1.f);
  convT<<<dim3(36,36),256,0,stream>>>(txt_w2, wT, 1152, 1152, nullptr);
  gemm_t<0,1,0,1><<<dim3(9,1,32),256,0,stream>>>(txth, wT, lat + 64*1152, txt_b2, nullptr,
      1152,1152,1152,1152, 64,1152,1152, 1, 64L*1152,0, 0,0, 128L*1152,0, 1.f);
  latcopy<<<9216,256,0,stream>>>(lat0, lat);

  ln_k<0><<<23328,256,0,stream>>>(x, xnorm, nullptr, nullptr, 1<<28, 0);

  for (int L=0; L<6; L++){
    const float* WqL  = Wq    + (size_t)L*1152*1536;
    const float* WkvL = Wkv   + (size_t)L*1152*3072;
    const float* WoL  = Wo    + (size_t)L*1536*1152;
    const float* fw1  = ff_w1 + (size_t)L*1152*4608;
    const float* fw2  = ff_w2 + (size_t)L*4608*1152;

    // lm = LN(lat; nl)
    ln_k<0><<<4096,256,0,stream>>>(lat, lm, nl_w + L*1152, nl_b + L*1152, 1<<28, 0);

    // weight transposes
    convT<<<dim3(48,36),256,0,stream>>>(WqL, wT, 1152, 1536, nullptr);
    convT2<<<dim3(96,36),256,0,stream>>>(WkvL, wTx, wT + 1536*1152, 1152, 3072, nm_w + L*1152);

    // fused q | kv-latent (M=4096, N=4608)
    gemm_v2<0,0,0,0,2,0><<<dim3(18,32),512,0,stream>>>(lm, wT, qb, kv, nullptr, nullptr,
        1152,1152,1152,0, 4096, 4608, 4608);

    // kv x part (M=23328 -> 184 M-blocks; clamp handles pad)
    biasfold<<<12,256,0,stream>>>(WkvL, nm_b + L*1152, biasf);
    gemm_v2<0,1,0,0,1,0><<<dim3(12,184),512,0,stream>>>(xnorm, wTx, kv, nullptr, biasf, nullptr,
        1152,1152,1152,0, 23328, 3072, 3072);

    // Vt = V^T per batch (zero-padded to 864 keys)
    transV<<<dim3(48,27,32),256,0,stream>>>(kv, Vt);

    // fused flash attention
    flash_attn<<<512,256,0,stream>>>(qb, kv, Vt, attn);

    // lat += attn @ Wo   (split-K x2 -> partials -> reduce)
    convT<<<dim3(36,48),256,0,stream>>>(WoL, wT, 1536, 1152, nullptr);
    gemm_v2<0,0,0,1,0,1><<<dim3(5,32,2),512,0,stream>>>(attn, wT, ppart, nullptr, nullptr, nullptr,
        768,1536,1536,1152, 4096, 1152, 1152);
    reduce2<<<2048,256,0,stream>>>(lat, ppart, 4096L*1152);

    // FF
    ln_k<0><<<4096,256,0,stream>>>(lat, lm, ffln_w + L*1152, ffln_b + L*1152, 1<<28, 0);
    convT<<<dim3(144,36),256,0,stream>>>(fw1, wT, 1152, 4608, nullptr);
    gemm_v2<1,0,0,0,0,0><<<dim3(18,32),512,0,stream>>>(lm, wT, ffh, nullptr, nullptr, nullptr,
        1152,1152,1152,4608, 4096, 4608, 4608);
    convT<<<dim3(36,144),256,0,stream>>>(fw2, wT, 4608, 1152, nullptr);
    gemm_v2<0,0,0,1,0,1><<<dim3(5,32,2),512,0,stream>>>(ffh, wT, ppart, nullptr, nullptr, nullptr,
        2304,4608,4608,1152, 4096, 1152, 1152);
    reduce2<<<2048,256,0,stream>>>(lat, ppart, 4096L*1152);
  }

  ln_k<1><<<2048,256,0,stream>>>(lat, out, oln_w, oln_b, 64, 128);
}

// Round 11
// 4442.721 us; speedup vs baseline: 1.3257x; 1.0272x over previous
//
#include <hip/hip_runtime.h>
#include <hip/hip_bf16.h>
#include <math.h>

// InstructPerceiverResampler on MI355X (gfx950).
// Round 11: (1) gemm_v2 M-INNER traversal (grid = (Mblocks, Nblocks)) so each
// XCD's contiguous block-chunk shares one B-panel (L2-resident); A re-reads
// absorb in L3. Fixes R10's kvx FETCH blowup (375 MB, B-panel thrash).
// (2) red2_ln fuses split-K reduce + row-LN (12 fewer dispatches, less lat
// round-trip). Tri-buffer pipeline, flash_attn, gemm_t unchanged.

typedef __attribute__((ext_vector_type(4))) float f32x4;
typedef __attribute__((ext_vector_type(8))) short bf16x8;
typedef unsigned int u32;

#define DEV __device__ __forceinline__

DEV float bf2f(short s){ union{u32 u; float f;} v; v.u = ((u32)(unsigned short)s) << 16; return v.f; }
DEV short f2bf(float f){
  union{float f; u32 u;} v; v.f = f;
  u32 r = (v.u + 0x7FFFu + ((v.u >> 16) & 1u)) >> 16;
  return (short)r;
}

DEV u32 lds_off(const short* p){
  return (u32)(uintptr_t)(__attribute__((address_space(3))) const short*)p;
}
template<int OFF>
DEV bf16x8 dsro(u32 addr){
  bf16x8 r;
  asm volatile("ds_read_b128 %0, %1 offset:%2" : "=v"(r) : "v"(addr), "i"(OFF));
  return r;
}

// ---------------------------------------------------------------------------
// gemm_v2: C[m,n] = A[m,k]*B[n,k] (+bias)(+gelu), tiles 128x256, BK=32.
// M-INNER grid: m0 = (bid % gridDim.x)*128, n0 = (bid / gridDim.x)*256.
// Triple-buffered LDS 72 KiB -> 2 blocks/CU; counted vmcnt(3), prefetch 2.
// ---------------------------------------------------------------------------
template<int GELU, int BIAS, int OUTF32, int CMAP, int KSPLIT>
__global__ __launch_bounds__(512, 4)
void gemm_v2(const short* __restrict__ A, const short* __restrict__ Bm,
             void* __restrict__ Cv, short* __restrict__ C2,
             const float* __restrict__ bias,
             int K, int lda, int ldb, int ldc,
             int Mvalid, int NBmax, int Nwrite)
{
  __shared__ __align__(16) short LDS[36864];   // 72 KiB: 3 bufs x (A 8KB | B 16KB)

  int nwg = gridDim.x * gridDim.y;
  int bid = blockIdx.y * gridDim.x + blockIdx.x;
  if ((nwg & 7) == 0){ int chunk = nwg >> 3; bid = (bid & 7)*chunk + (bid >> 3); }
  int by = bid / gridDim.x;
  int m0 = (bid - by*gridDim.x) * 128;   // M inner: consecutive bids share N-panel
  int n0 = by * 256;
  int kzoff = KSPLIT ? (int)blockIdx.z * K : 0;

  int tid = threadIdx.x, lane = tid & 63, w = tid >> 6;
  int wr = w >> 2, wc = w & 3;
  int rsel = lane & 15, g4 = lane >> 4;

  // ---- staging source pointers (loop-invariant) ----
  int sl = lane >> 3;
  int l  = (lane & 7) ^ sl;
  int lc = (l & 3) * 8;
  int lh = l >> 2;
  const short* gA;
  { int r = m0 + w*8 + sl + lh*64; if (r > Mvalid-1) r = Mvalid-1;
    gA = A + (long)r*lda + lc + kzoff; }
  const short* gB0;
  { int r = n0 + w*8 + sl + lh*128; if (r > NBmax-1) r = NBmax-1;
    gB0 = Bm + (long)r*ldb + lc + kzoff; }
  const short* gB1;
  { int r = n0 + 64 + w*8 + sl + lh*128; if (r > NBmax-1) r = NBmax-1;
    gB1 = Bm + (long)r*ldb + lc + kzoff; }
  char* dA  = (char*)LDS + w*1024;
  char* dB0 = (char*)LDS + 8192  + w*1024;
  char* dB1 = (char*)LDS + 16384 + w*1024;

#define GLDS(src, dst) __builtin_amdgcn_global_load_lds( \
      (const __attribute__((address_space(1))) u32*)(src), \
      (__attribute__((address_space(3))) u32*)(dst), 16, 0, 0)
#define STAGE(bo, tau) do { \
    int kb = (tau)*32; \
    GLDS(gA  + kb, dA  + (bo)); \
    GLDS(gB0 + kb, dB0 + (bo)); \
    GLDS(gB1 + kb, dB1 + (bo)); \
  } while(0)

  u32 base = lds_off(LDS);
  u32 aAddr = base + (u32)(rsel*128 + (((wr*4 + g4) ^ (rsel & 7))*16));
  u32 bAddr = base + 8192u
            + (u32)(((wc & 1)*64 + rsel)*128 + ((((wc >> 1)*4 + g4) ^ (rsel & 7))*16));

  int nt = K >> 5;

  f32x4 acc[4][4];
#pragma unroll
  for (int i=0;i<4;i++)
#pragma unroll
    for (int j=0;j<4;j++) acc[i][j] = (f32x4){0.f,0.f,0.f,0.f};

  STAGE(0u, 0);
  if (nt > 1) STAGE(24576u, 1);

  u32 boCur = 0;
#pragma unroll 1
  for (int t=0; t<nt; ++t){
    if (t == nt-1) { asm volatile("s_waitcnt vmcnt(0)" ::: "memory"); }
    else           { asm volatile("s_waitcnt vmcnt(3)" ::: "memory"); }
    asm volatile("s_barrier" ::: "memory");
    u32 aa = aAddr + boCur, bb = bAddr + boCur;
    bf16x8 af[4], bfr[4];
    af[0]  = dsro<0>(aa);    af[1]  = dsro<2048>(aa);
    af[2]  = dsro<4096>(aa); af[3]  = dsro<6144>(aa);
    bfr[0] = dsro<0>(bb);    bfr[1] = dsro<2048>(bb);
    bfr[2] = dsro<4096>(bb); bfr[3] = dsro<6144>(bb);
    if (t+2 < nt){
      u32 boN2 = boCur + 49152u; if (boN2 >= 73728u) boN2 -= 73728u;
      STAGE(boN2, t+2);
    }
    asm volatile("s_waitcnt lgkmcnt(0)" ::: "memory");
    __builtin_amdgcn_sched_barrier(0);
    __builtin_amdgcn_s_setprio(1);
#pragma unroll
    for (int mi=0; mi<4; mi++)
#pragma unroll
      for (int nn=0; nn<4; nn++)
        acc[mi][nn] = __builtin_amdgcn_mfma_f32_16x16x32_bf16(af[mi], bfr[nn], acc[mi][nn], 0, 0, 0);
    __builtin_amdgcn_s_setprio(0);
    boCur += 24576u; if (boCur == 73728u) boCur = 0;
  }
#undef STAGE
#undef GLDS

  // ---- epilogue: C/D frag layout col=lane&15, row=(lane>>4)*4+j ----
  int cq = g4 * 4;
  int csel = rsel;
#pragma unroll
  for (int mi=0; mi<4; mi++){
#pragma unroll
    for (int nn=0; nn<4; nn++){
#pragma unroll
      for (int j=0; j<4; j++){
        int gm = m0 + wr*64 + mi*16 + cq + j;
        int gn = n0 + wc*64 + nn*16 + csel;
        if (gm < Mvalid && gn < Nwrite){
          float v = acc[mi][nn][j];
          if (BIAS) v += bias[gn];
          if (GELU) v = 0.5f*v*(1.0f + erff(v*0.70710678118654752f));
          if (CMAP == 0){
            long off = (long)gm*ldc + gn;
            if (KSPLIT) off += (long)blockIdx.z * ((long)Mvalid * ldc);
            if (OUTF32) ((float*)Cv)[off] = v;
            else        ((short*)Cv)[off] = f2bf(v);
          } else if (CMAP == 1){
            int bb2 = gm / 729;
            int jj = gm - bb2*729;
            ((short*)Cv)[((long)bb2*857 + jj)*3072 + gn] = f2bf(v);
          } else {
            if (gn < 1536){
              ((short*)Cv)[(long)gm*1536 + gn] = f2bf(v * 0.1020620726159657f);
            } else {
              int bb2 = gm >> 7, jj = gm & 127;
              C2[((long)bb2*857 + 729 + jj)*3072 + (gn - 1536)] = f2bf(v);
            }
          }
        }
      }
    }
  }
}

// ---------------------------------------------------------------------------
// red2_ln: lat[r] += p0[r] + p1[r]  (split-K partials), then lm[r] = LN(lat[r]).
// One block per row. Replaces reduce2 + ln_k pair.
// ---------------------------------------------------------------------------
__global__ __launch_bounds__(256)
void red2_ln(float* __restrict__ lat, const float* __restrict__ p, long n,
             short* __restrict__ lm, const float* __restrict__ w,
             const float* __restrict__ b)
{
  const int D = 1152;
  int r = blockIdx.x;
  long rb = (long)r*D;
  int tid = threadIdx.x;
  float s1=0.f, s2=0.f;
  float xv[5];
#pragma unroll
  for (int t=0;t<5;t++){
    int i = tid + t*256;
    float v = 0.f;
    if (i < D){
      v = lat[rb+i] + p[rb+i] + p[n+rb+i];
      lat[rb+i] = v;
    }
    xv[t] = v; s1 += v; s2 += v*v;
  }
#pragma unroll
  for (int o=32;o;o>>=1){ s1 += __shfl_xor(s1,o); s2 += __shfl_xor(s2,o); }
  __shared__ float red[8];
  int wid = tid>>6, lane = tid&63;
  if (lane==0){ red[wid]=s1; red[4+wid]=s2; }
  __syncthreads();
  s1 = red[0]+red[1]+red[2]+red[3];
  s2 = red[4]+red[5]+red[6]+red[7];
  float mu = s1 / D;
  float var = s2 / D - mu*mu;
  float rs = rsqrtf(var + 1e-5f);
#pragma unroll
  for (int t=0;t<5;t++){
    int i = tid + t*256;
    if (i >= D) break;
    lm[rb+i] = f2bf((xv[t]-mu)*rs*w[i] + b[i]);
  }
}

// ---------------------------------------------------------------------------
// Flash attention (R8, verified): one block per (b,h). 4 waves x 32 q-rows.
// ---------------------------------------------------------------------------
__global__ __launch_bounds__(256)
void flash_attn(const short* __restrict__ qb, const short* __restrict__ kv,
                const short* __restrict__ Vtg, short* __restrict__ attn)
{
  __shared__ short Kt[96][104];
  __shared__ short Vs[96][104];
  __shared__ short Pb[4][32][104];
  __shared__ float FAC[128];

  int z = blockIdx.x;
  int b = z >> 4, h = z & 15;
  int tid = threadIdx.x;
  int lane = tid & 63;
  int w = tid >> 6;
  int l15 = lane & 15, g4 = lane >> 4;

  bf16x8 qf[2][3];
#pragma unroll
  for (int n=0;n<2;n++)
#pragma unroll
    for (int kf=0;kf<3;kf++)
      qf[n][kf] = *(const bf16x8*)&qb[((long)(b*128 + w*32 + n*16 + l15))*1536
                                     + h*96 + kf*32 + g4*8];

  f32x4 acc[2][6];
#pragma unroll
  for (int i=0;i<2;i++)
#pragma unroll
    for (int j=0;j<6;j++) acc[i][j] = (f32x4){0.f,0.f,0.f,0.f};
  float m_run[2] = {-1e30f, -1e30f};
  float l_run[2] = {0.f, 0.f};

  const short* kvb = kv  + (long)b*857*3072 + h*96;
  const short* vtb = Vtg + ((long)b*1536 + h*96)*864;

  for (int t=0; t<9; ++t){
    int k0 = t*96;
    for (int c = tid; c < 1152; c += 256){
      int r = c / 12;
      int c12 = c - r*12;
      int key = k0 + r; if (key > 856) key = 856;
      *(bf16x8*)&Kt[r][c12*8] = *(const bf16x8*)&kvb[(long)key*3072 + c12*8];
      *(bf16x8*)&Vs[r][c12*8] = *(const bf16x8*)&vtb[(long)r*864 + k0 + c12*8];
    }
    __syncthreads();

    f32x4 st[6][2];
#pragma unroll
    for (int m=0;m<6;m++){ st[m][0]=(f32x4){0,0,0,0}; st[m][1]=(f32x4){0,0,0,0}; }
#pragma unroll
    for (int kf=0;kf<3;kf++){
      bf16x8 af[6];
#pragma unroll
      for (int m=0;m<6;m++) af[m] = *(const bf16x8*)&Kt[m*16 + l15][kf*32 + g4*8];
#pragma unroll
      for (int m=0;m<6;m++){
        st[m][0] = __builtin_amdgcn_mfma_f32_16x16x32_bf16(af[m], qf[0][kf], st[m][0], 0,0,0);
        st[m][1] = __builtin_amdgcn_mfma_f32_16x16x32_bf16(af[m], qf[1][kf], st[m][1], 0,0,0);
      }
    }

    if (k0 + 96 > 857){
#pragma unroll
      for (int m=0;m<6;m++)
#pragma unroll
        for (int j=0;j<4;j++){
          if (k0 + m*16 + g4*4 + j > 856){ st[m][0][j] = -1e30f; st[m][1][j] = -1e30f; }
        }
    }

#pragma unroll
    for (int n=0;n<2;n++){
      float mx = -1e30f;
#pragma unroll
      for (int m=0;m<6;m++)
#pragma unroll
        for (int j=0;j<4;j++) mx = fmaxf(mx, st[m][n][j]);
      mx = fmaxf(mx, __shfl_xor(mx, 16));
      mx = fmaxf(mx, __shfl_xor(mx, 32));
      float mn = fmaxf(m_run[n], mx);
      float f  = __expf(m_run[n] - mn);
      m_run[n] = mn;
      float s = 0.f;
#pragma unroll
      for (int m=0;m<6;m++)
#pragma unroll
        for (int j=0;j<4;j++){
          float e = __expf(st[m][n][j] - mn);
          st[m][n][j] = e; s += e;
        }
      s += __shfl_xor(s, 16);
      s += __shfl_xor(s, 32);
      l_run[n] = l_run[n]*f + s;
      if (g4 == 0) FAC[w*32 + n*16 + l15] = f;
    }

#pragma unroll
    for (int m=0;m<6;m++)
#pragma unroll
      for (int n=0;n<2;n++){
        short4 pk;
        pk.x = f2bf(st[m][n][0]); pk.y = f2bf(st[m][n][1]);
        pk.z = f2bf(st[m][n][2]); pk.w = f2bf(st[m][n][3]);
        *(short4*)&Pb[w][n*16 + l15][m*16 + g4*4] = pk;
      }

    {
      float4 fj0 = *(const float4*)&FAC[w*32 +  0 + g4*4];
      float4 fj1 = *(const float4*)&FAC[w*32 + 16 + g4*4];
#pragma unroll
      for (int nn=0;nn<6;nn++){
        acc[0][nn][0] *= fj0.x; acc[0][nn][1] *= fj0.y;
        acc[0][nn][2] *= fj0.z; acc[0][nn][3] *= fj0.w;
        acc[1][nn][0] *= fj1.x; acc[1][nn][1] *= fj1.y;
        acc[1][nn][2] *= fj1.z; acc[1][nn][3] *= fj1.w;
      }
    }

#pragma unroll
    for (int kf=0;kf<3;kf++){
      bf16x8 pa0 = *(const bf16x8*)&Pb[w][ 0 + l15][kf*32 + g4*8];
      bf16x8 pa1 = *(const bf16x8*)&Pb[w][16 + l15][kf*32 + g4*8];
#pragma unroll
      for (int nn=0;nn<6;nn++){
        bf16x8 vb = *(const bf16x8*)&Vs[nn*16 + l15][kf*32 + g4*8];
        acc[0][nn] = __builtin_amdgcn_mfma_f32_16x16x32_bf16(pa0, vb, acc[0][nn], 0,0,0);
        acc[1][nn] = __builtin_amdgcn_mfma_f32_16x16x32_bf16(pa1, vb, acc[1][nn], 0,0,0);
      }
    }
    __syncthreads();
  }

  if (g4 == 0){
    FAC[w*32 +  0 + l15] = 1.0f / l_run[0];
    FAC[w*32 + 16 + l15] = 1.0f / l_run[1];
  }
  float4 li0 = *(const float4*)&FAC[w*32 +  0 + g4*4];
  float4 li1 = *(const float4*)&FAC[w*32 + 16 + g4*4];
  float li[2][4] = {{li0.x,li0.y,li0.z,li0.w},{li1.x,li1.y,li1.z,li1.w}};
#pragma unroll
  for (int mo=0;mo<2;mo++)
#pragma unroll
    for (int nn=0;nn<6;nn++)
#pragma unroll
      for (int j=0;j<4;j++){
        int q = w*32 + mo*16 + g4*4 + j;
        int d = nn*16 + l15;
        attn[((long)(b*128+q))*1536 + h*96 + d] = f2bf(acc[mo][nn][j]*li[mo][j]);
      }
}

// ---------------------------------------------------------------------------
// 128x128 2-phase GEMM (verified r2) for preamble shapes.
// ---------------------------------------------------------------------------
template<int GELU, int BIAS, int RES, int OUTF32>
__global__ __launch_bounds__(256)
void gemm_t(const short* __restrict__ A, const short* __restrict__ B,
            void* __restrict__ C, const float* __restrict__ bias,
            const float* __restrict__ res,
            int K, int lda, int ldb, int ldc,
            int Mvalid, int NBmax, int Nwrite,
            int zdiv, long sA1, long sA2, long sB1, long sB2, long sC1, long sC2,
            float scale)
{
  __shared__ __align__(16) short As[2][128*32];
  __shared__ __align__(16) short Bs[2][128*32];

  int z = blockIdx.z;
  int zq = z / zdiv, zr = z - zq*zdiv;
  const short* Ab = A + zq*sA1 + zr*sA2;
  const short* Bb = B + zq*sB1 + zr*sB2;
  long cOff = zq*sC1 + zr*sC2;
  int m0 = blockIdx.y * 128;
  int n0 = blockIdx.x * 128;
  int tid = threadIdx.x;
  int lane = tid & 63;
  int w = tid >> 6;
  int wm = (w >> 1) * 64, wn = (w & 1) * 64;

  int sr = lane >> 2;
  int sc = (lane & 3) * 8;
  int ar0 = m0 + w*32 + sr;
  int br0 = n0 + w*32 + sr;

  int raA0 = ar0;      if (raA0 > Mvalid-1) raA0 = Mvalid-1;
  int raA1 = ar0 + 16; if (raA1 > Mvalid-1) raA1 = Mvalid-1;
  int rbB0 = br0;      if (rbB0 > NBmax-1) rbB0 = NBmax-1;
  int rbB1 = br0 + 16; if (rbB1 > NBmax-1) rbB1 = NBmax-1;
  const short* gA0 = Ab + (long)raA0*lda + sc;
  const short* gA1 = Ab + (long)raA1*lda + sc;
  const short* gB0 = Bb + (long)rbB0*ldb + sc;
  const short* gB1 = Bb + (long)rbB1*ldb + sc;
  int ldsRow0 = (w*32)*32;
  int ldsRow1 = (w*32 + 16)*32;

  f32x4 acc[4][4];
#pragma unroll
  for (int i=0;i<4;i++)
#pragma unroll
    for (int j=0;j<4;j++) acc[i][j] = (f32x4){0.f,0.f,0.f,0.f};

  auto stage = [&](int buf, int kb){
    __builtin_amdgcn_global_load_lds(
        (const __attribute__((address_space(1))) u32*)(gA0 + kb),
        (__attribute__((address_space(3))) u32*)(&As[buf][ldsRow0]), 16, 0, 0);
    __builtin_amdgcn_global_load_lds(
        (const __attribute__((address_space(1))) u32*)(gA1 + kb),
        (__attribute__((address_space(3))) u32*)(&As[buf][ldsRow1]), 16, 0, 0);
    __builtin_amdgcn_global_load_lds(
        (const __attribute__((address_space(1))) u32*)(gB0 + kb),
        (__attribute__((address_space(3))) u32*)(&Bs[buf][ldsRow0]), 16, 0, 0);
    __builtin_amdgcn_global_load_lds(
        (const __attribute__((address_space(1))) u32*)(gB1 + kb),
        (__attribute__((address_space(3))) u32*)(&Bs[buf][ldsRow1]), 16, 0, 0);
  };

  int nt = K >> 5;
  stage(0, 0);
  __syncthreads();

  int kq = (lane >> 4) * 8;
  int rsel = lane & 15;
  int cur = 0;
  for (int t = 0; t < nt; ++t){
    if (t + 1 < nt) stage(cur ^ 1, (t+1)*32);

    bf16x8 af[4], bfr[4];
#pragma unroll
    for (int m=0;m<4;m++) af[m]  = *(const bf16x8*)&As[cur][(wm + m*16 + rsel)*32 + kq];
#pragma unroll
    for (int n=0;n<4;n++) bfr[n] = *(const bf16x8*)&Bs[cur][(wn + n*16 + rsel)*32 + kq];
#pragma unroll
    for (int m=0;m<4;m++)
#pragma unroll
      for (int n=0;n<4;n++)
        acc[m][n] = __builtin_amdgcn_mfma_f32_16x16x32_bf16(af[m], bfr[n], acc[m][n], 0, 0, 0);

    __syncthreads();
    cur ^= 1;
  }

  int cq = (lane >> 4) * 4;
  int csel = lane & 15;
#pragma unroll
  for (int m=0;m<4;m++){
#pragma unroll
    for (int n=0;n<4;n++){
#pragma unroll
      for (int j=0;j<4;j++){
        int gm = m0 + wm + m*16 + cq + j;
        int gn = n0 + wn + n*16 + csel;
        if (gm < Mvalid && gn < Nwrite){
          float v = acc[m][n][j] * scale;
          if (BIAS) v += bias[gn];
          if (GELU) v = 0.5f*v*(1.0f + erff(v*0.70710678118654752f));
          long off = cOff + (long)gm*ldc + gn;
          if (OUTF32){
            float rv = RES ? res[off] : 0.0f;
            ((float*)C)[off] = v + rv;
          } else {
            ((short*)C)[off] = f2bf(v);
          }
        }
      }
    }
  }
}

// ---------------------------------------------------------------------------
__global__ __launch_bounds__(256)
void convT(const float* __restrict__ in, short* __restrict__ out,
           int K, int N, const float* __restrict__ s)
{
  __shared__ float tile[32][33];
  int kb = blockIdx.y*32, nb = blockIdx.x*32;
  int tx = threadIdx.x & 31, ty = threadIdx.x >> 5;
  for (int i = ty; i < 32; i += 8){
    int k = kb + i, n = nb + tx;
    float v = 0.f;
    if (k < K && n < N){ v = in[(long)k*N + n]; if (s) v *= s[k]; }
    tile[i][tx] = v;
  }
  __syncthreads();
  for (int i = ty; i < 32; i += 8){
    int n = nb + i, k = kb + tx;
    if (n < N && k < K) out[(long)n*K + k] = f2bf(tile[tx][i]);
  }
}

__global__ __launch_bounds__(256)
void convT2(const float* __restrict__ in, short* __restrict__ out1,
            short* __restrict__ out2, int K, int N, const float* __restrict__ s)
{
  __shared__ float tile[32][33];
  __shared__ float sv[32];
  int kb = blockIdx.y*32, nb = blockIdx.x*32;
  int tx = threadIdx.x & 31, ty = threadIdx.x >> 5;
  if (threadIdx.x < 32){
    int k = kb + threadIdx.x;
    sv[threadIdx.x] = (k < K) ? s[k] : 0.f;
  }
  for (int i = ty; i < 32; i += 8){
    int k = kb + i, n = nb + tx;
    float v = 0.f;
    if (k < K && n < N) v = in[(long)k*N + n];
    tile[i][tx] = v;
  }
  __syncthreads();
  for (int i = ty; i < 32; i += 8){
    int n = nb + i, k = kb + tx;
    if (n < N && k < K){
      float v = tile[tx][i];
      out2[(long)n*K + k] = f2bf(v);
      out1[(long)n*K + k] = f2bf(v * sv[tx]);
    }
  }
}

__global__ __launch_bounds__(256)
void biasfold(const float* __restrict__ W, const float* __restrict__ bvec, float* __restrict__ outb)
{
  int n = blockIdx.x*256 + threadIdx.x;
  float s = 0.f;
  for (int k=0;k<1152;k++) s += bvec[k]*W[(long)k*3072 + n];
  outb[n] = s;
}

__global__ __launch_bounds__(256)
void cvt_bf16x4(const float* __restrict__ in, short* __restrict__ o, long n)
{
  long i = ((long)blockIdx.x*256 + threadIdx.x)*4;
  if (i >= n) return;
  float4 v = *(const float4*)(in + i);
  o[i+0]=f2bf(v.x); o[i+1]=f2bf(v.y); o[i+2]=f2bf(v.z); o[i+3]=f2bf(v.w);
}

__global__ __launch_bounds__(256)
void latcopy(const float* __restrict__ latents, float* __restrict__ lat)
{
  int idx = blockIdx.x*256 + threadIdx.x;
  int d = idx % 1152; int j = (idx / 1152) % 64; int b = idx / (1152*64);
  lat[((long)b*128 + j)*1152 + d] = latents[j*1152 + d];
}

__global__ __launch_bounds__(256)
void transV(const short* __restrict__ kv, short* __restrict__ Vt)
{
  int b = blockIdx.z;
  __shared__ short tile[32][33];
  int rb = blockIdx.y*32, cb = blockIdx.x*32;
  int tx = threadIdx.x & 31, ty = threadIdx.x >> 5;
  for (int i=ty; i<32; i+=8){
    int r = rb+i, c = cb+tx;
    short v = 0;
    if (r < 857) v = kv[((long)b*857 + r)*3072 + 1536 + c];
    tile[i][tx] = v;
  }
  __syncthreads();
  for (int i=ty;i<32;i+=8){
    int c = cb+i, r = rb+tx;
    Vt[((long)b*1536 + c)*864 + r] = tile[tx][i];
  }
}

template<int OUTF32>
__global__ __launch_bounds__(256)
void ln_k(const float* __restrict__ in, void* __restrict__ outp,
          const float* __restrict__ w, const float* __restrict__ b,
          int grpSel, int grpStride)
{
  const int D = 1152;
  int r = blockIdx.x;
  long ir = (long)(r / grpSel)*grpStride + (r % grpSel);
  const float* x = in + ir*D;
  int tid = threadIdx.x;
  float s1=0.f, s2=0.f;
  float xv[5];
#pragma unroll
  for (int t=0;t<5;t++){
    int i = tid + t*256;
    xv[t] = (i < D) ? x[i] : 0.f;
    s1 += xv[t]; s2 += xv[t]*xv[t];
  }
#pragma unroll
  for (int o=32;o;o>>=1){ s1 += __shfl_xor(s1,o); s2 += __shfl_xor(s2,o); }
  __shared__ float red[8];
  int wid = tid>>6, lane = tid&63;
  if (lane==0){ red[wid]=s1; red[4+wid]=s2; }
  __syncthreads();
  s1 = red[0]+red[1]+red[2]+red[3];
  s2 = red[4]+red[5]+red[6]+red[7];
  float mu = s1 / D;
  float var = s2 / D - mu*mu;
  float rs = rsqrtf(var + 1e-5f);
#pragma unroll
  for (int t=0;t<5;t++){
    int i = tid + t*256;
    if (i >= D) break;
    float v = (xv[t]-mu)*rs;
    if (w) v = v*w[i] + b[i];
    if (OUTF32) ((float*)outp)[(long)r*D + i] = v;
    else        ((short*)outp)[(long)r*D + i] = f2bf(v);
  }
}

// ---------------------------------------------------------------------------

extern "C" void kernel_launch(void* const* d_in, const int* in_sizes, int n_in,
                              void* d_out, int out_size, void* d_ws, size_t ws_size,
                              hipStream_t stream)
{
  const float* x      = (const float*)d_in[0];
  const float* tein   = (const float*)d_in[1];
  const float* lat0   = (const float*)d_in[2];
  const float* txt_w1 = (const float*)d_in[3];
  const float* txt_b1 = (const float*)d_in[4];
  const float* txt_w2 = (const float*)d_in[5];
  const float* txt_b2 = (const float*)d_in[6];
  const float* nm_w   = (const float*)d_in[7];
  const float* nm_b   = (const float*)d_in[8];
  const float* nl_w   = (const float*)d_in[9];
  const float* nl_b   = (const float*)d_in[10];
  const float* Wq     = (const float*)d_in[11];
  const float* Wkv    = (const float*)d_in[12];
  const float* Wo     = (const float*)d_in[13];
  const float* ffln_w = (const float*)d_in[14];
  const float* ffln_b = (const float*)d_in[15];
  const float* ff_w1  = (const float*)d_in[16];
  const float* ff_w2  = (const float*)d_in[17];
  const float* oln_w  = (const float*)d_in[18];
  const float* oln_b  = (const float*)d_in[19];
  float* out = (float*)d_out;
  (void)in_sizes; (void)n_in; (void)out_size; (void)ws_size;

  char* base = (char*)d_ws;
  size_t off = 0;
  auto alloc = [&](size_t bytes)->char*{
    char* r = base + off;
    off += (bytes + 255) & ~(size_t)255;
    return r;
  };
  short* wT    = (short*)alloc(4608ULL*1152*2);
  short* wTx   = (short*)alloc(3072ULL*1152*2);
  float* biasf = (float*)alloc(3072*4);
  float* ppart = (float*)alloc(2ULL*4096*1152*4);
  short* xnorm = (short*)alloc(23328ULL*1152*2);
  float* lat   = (float*)alloc(4096ULL*1152*4);
  short* lm    = (short*)alloc(4096ULL*1152*2);
  short* qb    = (short*)alloc(4096ULL*1536*2);
  short* kv    = (short*)alloc(27424ULL*3072*2);
  short* Vt    = (short*)alloc(32ULL*1536*864*2);
  short* SP    = (short*)alloc(2048ULL*4096*2 + 2048ULL*1152*2);
  short* attn  = (short*)alloc(4096ULL*1536*2);
  short* ffh   = (short*)alloc(4096ULL*4608*2);
  short* txtin = SP;
  short* txth  = SP + 2048ULL*4096;

  // ---- preamble ----
  cvt_bf16x4<<<8192,256,0,stream>>>(tein, txtin, 2048LL*4096);
  convT<<<dim3(36,128),256,0,stream>>>(txt_w1, wT, 4096, 1152, nullptr);
  gemm_t<1,1,0,0><<<dim3(9,16,1),256,0,stream>>>(txtin, wT, txth, txt_b1, nullptr,
      4096,4096,4096,1152, 2048,1152,1152, 1, 0,0,0,0,0,0, 1.f);
  convT<<<dim3(36,36),256,0,stream>>>(txt_w2, wT, 1152, 1152, nullptr);
  gemm_t<0,1,0,1><<<dim3(9,1,32),256,0,stream>>>(txth, wT, lat + 64*1152, txt_b2, nullptr,
      1152,1152,1152,1152, 64,1152,1152, 1, 64L*1152,0, 0,0, 128L*1152,0, 1.f);
  latcopy<<<9216,256,0,stream>>>(lat0, lat);

  ln_k<0><<<23328,256,0,stream>>>(x, xnorm, nullptr, nullptr, 1<<28, 0);
  // lm = LN(lat; nl[0])  (subsequent layers' nl-LN comes fused from red2_ln)
  ln_k<0><<<4096,256,0,stream>>>(lat, lm, nl_w, nl_b, 1<<28, 0);

  for (int L=0; L<6; L++){
    const float* WqL  = Wq    + (size_t)L*1152*1536;
    const float* WkvL = Wkv   + (size_t)L*1152*3072;
    const float* WoL  = Wo    + (size_t)L*1536*1152;
    const float* fw1  = ff_w1 + (size_t)L*1152*4608;
    const float* fw2  = ff_w2 + (size_t)L*4608*1152;
    int Ln = (L+1 < 6) ? (L+1) : 5;   // nl index for fused next-layer LN (L=5: dead)

    // weight transposes
    convT<<<dim3(48,36),256,0,stream>>>(WqL, wT, 1152, 1536, nullptr);
    convT2<<<dim3(96,36),256,0,stream>>>(WkvL, wTx, wT + 1536*1152, 1152, 3072, nm_w + L*1152);

    // fused q | kv-latent (M-inner grid: (Mb=32, Nb=18))
    gemm_v2<0,0,0,2,0><<<dim3(32,18),512,0,stream>>>(lm, wT, qb, kv, nullptr,
        1152,1152,1152,0, 4096, 4608, 4608);

    // kv x part (M-inner grid: (Mb=184, Nb=12))
    biasfold<<<12,256,0,stream>>>(WkvL, nm_b + L*1152, biasf);
    gemm_v2<0,1,0,1,0><<<dim3(184,12),512,0,stream>>>(xnorm, wTx, kv, nullptr, biasf,
        1152,1152,1152,0, 23328, 3072, 3072);

    // Vt = V^T per batch (zero-padded to 864 keys)
    transV<<<dim3(48,27,32),256,0,stream>>>(kv, Vt);

    // fused flash attention
    flash_attn<<<512,256,0,stream>>>(qb, kv, Vt, attn);

    // lat += attn @ Wo (split-K x2 -> partials), fused reduce + ffln-LN
    convT<<<dim3(36,48),256,0,stream>>>(WoL, wT, 1536, 1152, nullptr);
    gemm_v2<0,0,1,0,1><<<dim3(32,5,2),512,0,stream>>>(attn, wT, ppart, nullptr, nullptr,
        768,1536,1536,1152, 4096, 1152, 1152);
    red2_ln<<<4096,256,0,stream>>>(lat, ppart, 4096L*1152, lm,
        ffln_w + L*1152, ffln_b + L*1152);

    // FF
    convT<<<dim3(144,36),256,0,stream>>>(fw1, wT, 1152, 4608, nullptr);
    gemm_v2<1,0,0,0,0><<<dim3(32,18),512,0,stream>>>(lm, wT, ffh, nullptr, nullptr,
        1152,1152,1152,4608, 4096, 4608, 4608);
    convT<<<dim3(36,144),256,0,stream>>>(fw2, wT, 4608, 1152, nullptr);
    gemm_v2<0,0,1,0,1><<<dim3(32,5,2),512,0,stream>>>(ffh, wT, ppart, nullptr, nullptr,
        2304,4608,4608,1152, 4096, 1152, 1152);
    // lat += ff-out; lm = LN(lat; nl[L+1]) for next layer (L=5: lm dead)
    red2_ln<<<4096,256,0,stream>>>(lat, ppart, 4096L*1152, lm,
        nl_w + Ln*1152, nl_b + Ln*1152);
  }

  ln_k<1><<<2048,256,0,stream>>>(lat, out, oln_w, oln_b, 64, 128);
}